// Round 10
// baseline (4960.921 us; speedup 1.0000x reference)
//
#include <hip/hip_runtime.h>

#define HB 65536  // 128*512 elements per [b][512] state plane
#define NBLK 256

typedef unsigned short u16;
typedef unsigned long long u64;
typedef __attribute__((ext_vector_type(8))) short bf16x8;
typedef __attribute__((ext_vector_type(8))) _Float16 f16x8;
typedef __attribute__((ext_vector_type(4))) float f32x4;
typedef __attribute__((ext_vector_type(2))) unsigned long long u64x2;
typedef __attribute__((ext_vector_type(8))) short s16x8;

#define MFMA_F16(a, b, c) __builtin_amdgcn_mfma_f32_16x16x32_f16(a, b, c, 0, 0, 0)
#define MFMA_BF16(a, b, c) __builtin_amdgcn_mfma_f32_16x16x32_bf16(a, b, c, 0, 0, 0)

__device__ __forceinline__ float fsig(float x) { return 1.f / (1.f + __expf(-x)); }
__device__ __forceinline__ float ftanh(float x) {
  float e = __expf(2.f * x);
  return 1.f - 2.f / (e + 1.f);
}
__device__ __forceinline__ u16 f2bf(float f) {
  unsigned u = __builtin_bit_cast(unsigned, f);
  return (u16)((u + 0x7FFFu + ((u >> 16) & 1)) >> 16);
}
__device__ __forceinline__ float bf2f(u16 h) {
  unsigned u = ((unsigned)h) << 16;
  return __builtin_bit_cast(float, u);
}
__device__ __forceinline__ u16 f2h(float f) {
  _Float16 h = (_Float16)f;
  return __builtin_bit_cast(u16, h);
}

// ---- coherence-point atomics (bypass non-coherent caches) ----
__device__ __forceinline__ u64 at_ld64(const void* p) {
  return __hip_atomic_load((const u64*)p, __ATOMIC_RELAXED, __HIP_MEMORY_SCOPE_AGENT);
}
__device__ __forceinline__ void at_st64(void* p, u64 v) {
  __hip_atomic_store((u64*)p, v, __ATOMIC_RELAXED, __HIP_MEMORY_SCOPE_AGENT);
}
__device__ __forceinline__ unsigned at_ld32(const void* p) {
  return __hip_atomic_load((const unsigned*)p, __ATOMIC_RELAXED, __HIP_MEMORY_SCOPE_AGENT);
}
__device__ __forceinline__ void at_st32(void* p, unsigned v) {
  __hip_atomic_store((unsigned*)p, v, __ATOMIC_RELAXED, __HIP_MEMORY_SCOPE_AGENT);
}
__device__ __forceinline__ u64 pk4(u16 a, u16 b, u16 c, u16 d) {
  return (u64)a | ((u64)b << 16) | ((u64)c << 32) | ((u64)d << 48);
}
__device__ __forceinline__ u64 pkf2(float a, float b) {
  return (u64)__builtin_bit_cast(unsigned, a) | ((u64)__builtin_bit_cast(unsigned, b) << 32);
}

// ---- pack weights [2048][K] fp32 -> fragment-major hi/lo ----
template <bool F16>
__global__ void pack_w(const float* __restrict__ W, u16* __restrict__ dst, int K) {
  int NKT = K >> 5;
  long gid = (long)blockIdx.x * 256 + threadIdx.x;
  long total = (long)128 * NKT * 64;
  if (gid >= total) return;
  int lane = gid & 63;
  int kt = (gid >> 6) % NKT;
  int rt = (gid >> 6) / NKT;
  int r = lane & 15;
  int grow = (r >> 2) * 512 + rt * 4 + (r & 3);
  int k0 = kt * 32 + (lane >> 4) * 8;
  long base = ((long)(rt * NKT + kt) * 2) * 512 + lane * 8;
#pragma unroll
  for (int e = 0; e < 8; ++e) {
    float w = W[(long)grow * K + k0 + e];
    u16 hi, lo;
    if (F16) {
      _Float16 h = (_Float16)w;
      hi = __builtin_bit_cast(u16, h);
      _Float16 l2 = (_Float16)(w - (float)h);
      lo = __builtin_bit_cast(u16, l2);
    } else {
      hi = f2bf(w);
      lo = f2bf(w - bf2f(hi));
    }
    dst[base + e] = hi;
    dst[base + 512 + e] = lo;
  }
}

__global__ void pack_x(const float* __restrict__ x, u16* __restrict__ xp) {
  long gid = (long)blockIdx.x * 256 + threadIdx.x;
  if (gid >= 128L * 256 * 64) return;
  int k = gid & 63;
  long bt = gid >> 6;
  int t = bt & 255;
  int b = bt >> 8;
  xp[((long)t * 128 + b) * 64 + k] = f2h(x[((long)b * 256 + t) * 64 + k]);
}

__global__ void pack_bias(const float* __restrict__ b0f, const float* __restrict__ b0b,
                          const float* __restrict__ b1f, const float* __restrict__ b1b,
                          float* __restrict__ bp) {
  int gid = blockIdx.x * 256 + threadIdx.x;
  if (gid >= 8192) return;
  int src = gid >> 11;
  int idx = gid & 2047;
  int rt = idx >> 4, rr = idx & 15;
  int grow = (rr >> 2) * 512 + rt * 4 + (rr & 3);
  const float* B = (src == 0) ? b0f : (src == 1) ? b0b : (src == 2) ? b1f : b1b;
  bp[gid] = B[grow];
}

#define C_TRANS 0
#define C_FIN 64  // separate cache line

// ---- persistent kernel. RING=1: per-step never-reused h buffers, plain cached staging.
template <int RING>
__global__ __launch_bounds__(512, 1) void lstm_persist(
    const u16* __restrict__ xpack, u16* __restrict__ h0arch,
    u16* __restrict__ h0bhi, u16* __restrict__ h0blo,
    u16* __restrict__ h1rhi, u16* __restrict__ h1rlo,
    const u16* __restrict__ wih0f_p, const u16* __restrict__ wih0b_p,
    const u16* __restrict__ whh0f_p, const u16* __restrict__ whh0b_p,
    const u16* __restrict__ wih1f_p, const u16* __restrict__ whh1f_p,
    const u16* __restrict__ wih1b_p, const u16* __restrict__ whh1b_p,
    const float* __restrict__ biasP,
    u16* __restrict__ hl0, u16* __restrict__ hl1,
    float* __restrict__ h1bf32,
    const float* __restrict__ fcw, const float* __restrict__ fcb,
    float* __restrict__ out,
    unsigned* __restrict__ flagsA, unsigned* __restrict__ flagsB,
    unsigned* __restrict__ cnt) {
  const int bid = blockIdx.x;
  const int xcd = bid & 7, slot = bid >> 3;
  const int tid = threadIdx.x;
  const int wid = tid >> 6, l = tid & 63;
  const int c = l & 15, q = l >> 4;

  __shared__ __align__(16) char smem[65536];   // h staging: [hi 32K | lo 32K]
  __shared__ __align__(16) f32x4 shacc[512];   // 8 KB reduce buffer

  const f32x4 fz = {0.f, 0.f, 0.f, 0.f};

  auto arriveflag = [&](unsigned* fl, unsigned gen) {
    asm volatile("s_waitcnt vmcnt(0)" ::: "memory");  // sc1 data stores at L3
    __syncthreads();
    if (tid == 0) at_st32(fl + (long)bid * 64, gen);
  };
  auto waitflags = [&](const unsigned* fl, int base, int nmem, unsigned gen) {
    if (wid == 0) {
      unsigned f;
      do {
        __builtin_amdgcn_s_sleep(1);
        f = (l < nmem) ? at_ld32(fl + (long)(base + l) * 64) : gen;
      } while (__ballot(f < gen));
    }
    __syncthreads();
  };
  auto arrivecnt = [&](int idx) {
    asm volatile("s_waitcnt vmcnt(0)" ::: "memory");
    __syncthreads();
    if (tid == 0)
      __hip_atomic_fetch_add(cnt + idx, 1u, __ATOMIC_RELAXED, __HIP_MEMORY_SCOPE_AGENT);
  };
  auto waitcnt_ = [&](int idx, unsigned tgt) {
    if (tid == 0) {
      while (at_ld32(cnt + idx) < tgt) __builtin_amdgcn_s_sleep(1);
    }
    __syncthreads();
  };

  // ================= Phase L0: 256 steps, both dirs, 8 groups of 32 =================
  {
    const int d = slot >> 4;
    const int bg = (slot >> 2) & 3;
    const int gbase = d * 128 + bg * 32;
    const int ug = xcd * 4 + (slot & 3);
    const int rowt = ug * 4 + (wid >> 1);
    const int btl = wid & 1;
    const int b0 = bg * 32 + btl * 16;
    const int bl = btl * 16 + c;
    const int blsw = (bl & 7) << 4;
    const u16* wxp = d ? wih0b_p : wih0f_p;
    const u16* whp = d ? whh0b_p : whh0f_p;
    const float* bp = biasP + ((long)d * 128 + rowt) * 16 + q * 4;
    float c_reg[4] = {0.f, 0.f, 0.f, 0.f};
    for (int s = 0; s < 256; ++s) {
      const int t = d ? 255 - s : s;
      const int par = s & 1;
      // x-projection FIRST (f16): overlaps other blocks' arrival
      f32x4 a0 = fz, a1 = fz;
      {
        const u16* bbase = xpack + ((long)t * 128 + b0 + c) * 64 + q * 8;
#pragma unroll
        for (int kt = 0; kt < 2; ++kt) {
          const u16* a = wxp + ((long)(rowt * 2 + kt) * 2) * 512 + l * 8;
          f16x8 ahi = *(const f16x8*)a;
          f16x8 alo = *(const f16x8*)(a + 512);
          f16x8 bx = *(const f16x8*)(bbase + kt * 32);
          f32x4& t0 = kt ? a1 : a0;
          t0 = MFMA_F16(ahi, bx, t0);
          t0 = MFMA_F16(alo, bx, t0);
        }
      }
      if (s) {
        waitflags(flagsA, gbase, 32, s);
        if (RING) {
          const int tp = d ? 256 - s : s - 1;
          const u16* rh = h0bhi + ((long)tp * 128 + bg * 32) * 1024 + d * 512;
          const u16* rl2 = h0blo + ((long)tp * 128 + bg * 32) * 1024 + d * 512;
#pragma unroll
          for (int i = 0; i < 8; ++i) {
            int m = tid + (i << 9);
            int pl = m >> 11, r = m & 2047;
            int b = r >> 6, k16 = r & 63;
            const u16* src = (pl ? rl2 : rh) + (long)b * 1024 + k16 * 8;
            u64x2 v = *(const u64x2*)src;  // plain cached load: line never reused -> fresh
            int dst = pl * 32768 + (((b << 10) | (k16 << 4)) ^ ((b & 7) << 4));
            *(u64x2*)(smem + dst) = v;
          }
        } else {
          const u16* hp_hi = hl0 + ((long)(par * 2 + d) * 2) * HB;
          const u16* hp_lo = hp_hi + HB;
#pragma unroll
          for (int i = 0; i < 8; ++i) {
            int m = tid + (i << 9);
            int pl = m >> 11, r = m & 2047;
            int b = r >> 6, k16 = r & 63;
            const u16* src = (pl ? hp_lo : hp_hi) + (long)(bg * 32 + b) * 512 + k16 * 8;
            u64x2 v;
            v.x = at_ld64(src);
            v.y = at_ld64(src + 4);
            int dst = pl * 32768 + (((b << 10) | (k16 << 4)) ^ ((b & 7) << 4));
            *(u64x2*)(smem + dst) = v;
          }
        }
        __syncthreads();
#pragma unroll
        for (int kt = 0; kt < 16; ++kt) {
          const u16* a = whp + ((long)(rowt * 16 + kt) * 2) * 512 + l * 8;
          bf16x8 ahi = *(const bf16x8*)a;
          bf16x8 alo = *(const bf16x8*)(a + 512);
          int base = ((bl << 10) | (kt << 6) | (q << 4)) ^ blsw;
          bf16x8 bhi = *(const bf16x8*)(smem + base);
          bf16x8 blo = *(const bf16x8*)(smem + 32768 + base);
          f32x4& t0 = (kt & 1) ? a1 : a0;
          t0 = MFMA_BF16(ahi, bhi, t0);
          t0 = MFMA_BF16(alo, bhi, t0);
          t0 = MFMA_BF16(ahi, blo, t0);
        }
        __syncthreads();
      }
      f32x4 acc = a0 + a1;
      float pre[4];
#pragma unroll
      for (int i = 0; i < 4; ++i) pre[i] = acc[i] + bp[i];
      const int par_w = par ^ 1;
      const int b = b0 + c;
      u16 pbh[4], pbl[4], pf[4];
#pragma unroll
      for (int i = 0; i < 4; ++i) {
        float gI = __shfl(pre[i], c);
        float gF = __shfl(pre[i], c + 16);
        float gG = __shfl(pre[i], c + 32);
        float gO = __shfl(pre[i], c + 48);
        float cn = fsig(gF) * c_reg[i] + fsig(gI) * ftanh(gG);
        c_reg[i] = cn;
        float hv = fsig(gO) * ftanh(cn);
        u16 hh = f2bf(hv);
        pbh[i] = hh;
        pbl[i] = f2bf(hv - bf2f(hh));
        pf[i] = RING ? (u16)0 : f2h(hv);
      }
      if (q == 0) {
        if (RING) {
          long off = ((long)t * 128 + b) * 1024 + d * 512 + rowt * 4;
          at_st64(h0bhi + off, pk4(pbh[0], pbh[1], pbh[2], pbh[3]));
          at_st64(h0blo + off, pk4(pbl[0], pbl[1], pbl[2], pbl[3]));
        } else {
          u16* hn_hi = hl0 + ((long)(par_w * 2 + d) * 2) * HB;
          u16* hn_lo = hn_hi + HB;
          if (s < 255) {
            at_st64(hn_hi + (long)b * 512 + rowt * 4, pk4(pbh[0], pbh[1], pbh[2], pbh[3]));
            at_st64(hn_lo + (long)b * 512 + rowt * 4, pk4(pbl[0], pbl[1], pbl[2], pbl[3]));
          }
          at_st64(h0arch + ((long)t * 128 + b) * 1024 + d * 512 + rowt * 4,
                  pk4(pf[0], pf[1], pf[2], pf[3]));
        }
      }
      if (s < 255) arriveflag(flagsA, (unsigned)(s + 1));
      else arrivecnt(C_TRANS);
    }
  }
  waitcnt_(C_TRANS, NBLK);
  __threadfence();  // one-time wb+inv: cross-phase h0 reads see fresh data
  __syncthreads();

  // L1 partition constants
  const int ug1 = xcd * 8 + (slot & 7);
  const int bg1 = slot >> 3;
  const int rl1 = (wid >> 1) & 1;
  const int btl1 = wid & 1;
  const int kh = wid >> 2;
  const int rowt1 = ug1 * 2 + rl1;
  const int b01 = bg1 * 32 + btl1 * 16;
  const int bl1 = btl1 * 16 + c;
  const int blsw1 = (bl1 & 7) << 4;

  // ================= Phase L1B: single step t=255 (zero state) =================
  {
    f32x4 a0 = fz, a1 = fz;
    if (RING) {
      const u16* bh = h0bhi + (255L * 128 + b01 + c) * 1024 + q * 8;
      const u16* bl2 = h0blo + (255L * 128 + b01 + c) * 1024 + q * 8;
#pragma unroll
      for (int kk = 0; kk < 16; ++kk) {
        int kt = kh * 16 + kk;
        const u16* a = wih1b_p + ((long)(rowt1 * 32 + kt) * 2) * 512 + l * 8;
        bf16x8 ahi = *(const bf16x8*)a;
        bf16x8 alo = *(const bf16x8*)(a + 512);
        bf16x8 bhi = *(const bf16x8*)(bh + kt * 32);
        bf16x8 blo = *(const bf16x8*)(bl2 + kt * 32);
        f32x4& t0 = (kk & 1) ? a1 : a0;
        t0 = MFMA_BF16(ahi, bhi, t0);
        t0 = MFMA_BF16(alo, bhi, t0);
        t0 = MFMA_BF16(ahi, blo, t0);
      }
    } else {
      const u16* bbase = h0arch + (255L * 128 + b01 + c) * 1024 + q * 8;
#pragma unroll
      for (int kk = 0; kk < 16; ++kk) {
        int kt = kh * 16 + kk;
        const u16* a = wih1b_p + ((long)(rowt1 * 32 + kt) * 2) * 512 + l * 8;
        f16x8 ahi = *(const f16x8*)a;
        f16x8 alo = *(const f16x8*)(a + 512);
        f16x8 bx = *(const f16x8*)(bbase + kt * 32);
        f32x4& t0 = (kk & 1) ? a1 : a0;
        t0 = MFMA_F16(ahi, bx, t0);
        t0 = MFMA_F16(alo, bx, t0);
      }
    }
    f32x4 acc = a0 + a1;
    shacc[wid * 64 + l] = acc;
    __syncthreads();
    if (wid < 4) {
      f32x4 tot = shacc[wid * 64 + l] + shacc[(wid + 4) * 64 + l];
      const float* bp1 = biasP + (3L * 128 + rowt1) * 16 + q * 4;
      float pre[4];
#pragma unroll
      for (int i = 0; i < 4; ++i) pre[i] = tot[i] + bp1[i];
      const int b = b01 + c;
      float hv[4];
#pragma unroll
      for (int i = 0; i < 4; ++i) {
        float gI = __shfl(pre[i], c);
        float gG = __shfl(pre[i], c + 32);
        float gO = __shfl(pre[i], c + 48);
        float cn = fsig(gI) * ftanh(gG);
        hv[i] = fsig(gO) * ftanh(cn);
      }
      if (q == 0) {
        at_st64((u16*)(h1bf32 + (long)b * 512 + rowt1 * 4), pkf2(hv[0], hv[1]));
        at_st64((u16*)(h1bf32 + (long)b * 512 + rowt1 * 4 + 2), pkf2(hv[2], hv[3]));
      }
    }
    __syncthreads();
  }

  // ================= Phase L1F: 256 steps forward, 4 groups of 64 ==========
  {
    const int g1base = bg1 * 64;
    float c_reg[4] = {0.f, 0.f, 0.f, 0.f};
    for (int s = 0; s < 256; ++s) {
      const int par = s & 1;
      f32x4 a0 = fz, a1 = fz;
      // h0 projection FIRST: overlaps arrival
      if (RING) {
        const u16* bh = h0bhi + ((long)s * 128 + b01 + c) * 1024 + q * 8;
        const u16* bl2 = h0blo + ((long)s * 128 + b01 + c) * 1024 + q * 8;
#pragma unroll
        for (int kk = 0; kk < 16; ++kk) {
          int kt = kh * 16 + kk;
          const u16* a = wih1f_p + ((long)(rowt1 * 32 + kt) * 2) * 512 + l * 8;
          bf16x8 ahi = *(const bf16x8*)a;
          bf16x8 alo = *(const bf16x8*)(a + 512);
          bf16x8 bhi = *(const bf16x8*)(bh + kt * 32);
          bf16x8 blo = *(const bf16x8*)(bl2 + kt * 32);
          f32x4& t0 = (kk & 1) ? a1 : a0;
          t0 = MFMA_BF16(ahi, bhi, t0);
          t0 = MFMA_BF16(alo, bhi, t0);
          t0 = MFMA_BF16(ahi, blo, t0);
        }
      } else {
        const u16* bbase = h0arch + ((long)s * 128 + b01 + c) * 1024 + q * 8;
#pragma unroll
        for (int kk = 0; kk < 16; ++kk) {
          int kt = kh * 16 + kk;
          const u16* a = wih1f_p + ((long)(rowt1 * 32 + kt) * 2) * 512 + l * 8;
          f16x8 ahi = *(const f16x8*)a;
          f16x8 alo = *(const f16x8*)(a + 512);
          f16x8 bx = *(const f16x8*)(bbase + kt * 32);
          f32x4& t0 = (kk & 1) ? a1 : a0;
          t0 = MFMA_F16(ahi, bx, t0);
          t0 = MFMA_F16(alo, bx, t0);
        }
      }
      if (s) {
        waitflags(flagsB, g1base, 64, s);
        if (RING) {
          const u16* rh = h1rhi + ((long)(s - 1) * 128 + bg1 * 32) * 512;
          const u16* rl2 = h1rlo + ((long)(s - 1) * 128 + bg1 * 32) * 512;
#pragma unroll
          for (int i = 0; i < 8; ++i) {
            int m = tid + (i << 9);
            int pl = m >> 11, r = m & 2047;
            int b = r >> 6, k16 = r & 63;
            const u16* src = (pl ? rl2 : rh) + (long)b * 512 + k16 * 8;
            u64x2 v = *(const u64x2*)src;
            int dst = pl * 32768 + (((b << 10) | (k16 << 4)) ^ ((b & 7) << 4));
            *(u64x2*)(smem + dst) = v;
          }
        } else {
          const u16* hp_hi = hl1 + (long)(par * 2) * HB;
          const u16* hp_lo = hp_hi + HB;
#pragma unroll
          for (int i = 0; i < 8; ++i) {
            int m = tid + (i << 9);
            int pl = m >> 11, r = m & 2047;
            int b = r >> 6, k16 = r & 63;
            const u16* src = (pl ? hp_lo : hp_hi) + (long)(bg1 * 32 + b) * 512 + k16 * 8;
            u64x2 v;
            v.x = at_ld64(src);
            v.y = at_ld64(src + 4);
            int dst = pl * 32768 + (((b << 10) | (k16 << 4)) ^ ((b & 7) << 4));
            *(u64x2*)(smem + dst) = v;
          }
        }
        __syncthreads();
#pragma unroll
        for (int kk = 0; kk < 8; ++kk) {
          int kt = kh * 8 + kk;
          const u16* a = whh1f_p + ((long)(rowt1 * 16 + kt) * 2) * 512 + l * 8;
          bf16x8 ahi = *(const bf16x8*)a;
          bf16x8 alo = *(const bf16x8*)(a + 512);
          int base = ((bl1 << 10) | (kt << 6) | (q << 4)) ^ blsw1;
          bf16x8 bhi = *(const bf16x8*)(smem + base);
          bf16x8 blo = *(const bf16x8*)(smem + 32768 + base);
          f32x4& t0 = (kk & 1) ? a1 : a0;
          t0 = MFMA_BF16(ahi, bhi, t0);
          t0 = MFMA_BF16(alo, bhi, t0);
          t0 = MFMA_BF16(ahi, blo, t0);
        }
        __syncthreads();
      }
      f32x4 acc = a0 + a1;
      shacc[wid * 64 + l] = acc;
      __syncthreads();
      if (wid < 4) {
        f32x4 tot = shacc[wid * 64 + l] + shacc[(wid + 4) * 64 + l];
        const float* bp1 = biasP + (2L * 128 + rowt1) * 16 + q * 4;
        float pre[4];
#pragma unroll
        for (int i = 0; i < 4; ++i) pre[i] = tot[i] + bp1[i];
        const int par_w = par ^ 1;
        const int b = b01 + c;
        u16 pbh[4], pbl[4];
#pragma unroll
        for (int i = 0; i < 4; ++i) {
          float gI = __shfl(pre[i], c);
          float gF = __shfl(pre[i], c + 16);
          float gG = __shfl(pre[i], c + 32);
          float gO = __shfl(pre[i], c + 48);
          float cn = fsig(gF) * c_reg[i] + fsig(gI) * ftanh(gG);
          c_reg[i] = cn;
          float hv = fsig(gO) * ftanh(cn);
          u16 hh = f2bf(hv);
          pbh[i] = hh;
          pbl[i] = f2bf(hv - bf2f(hh));
        }
        if (q == 0) {
          if (RING) {
            long off = ((long)s * 128 + b) * 512 + rowt1 * 4;
            at_st64(h1rhi + off, pk4(pbh[0], pbh[1], pbh[2], pbh[3]));
            at_st64(h1rlo + off, pk4(pbl[0], pbl[1], pbl[2], pbl[3]));
          } else {
            u16* hn_hi = hl1 + (long)(par_w * 2) * HB;
            u16* hn_lo = hn_hi + HB;
            if (s < 255) {
              at_st64(hn_hi + (long)b * 512 + rowt1 * 4, pk4(pbh[0], pbh[1], pbh[2], pbh[3]));
              at_st64(hn_lo + (long)b * 512 + rowt1 * 4, pk4(pbl[0], pbl[1], pbl[2], pbl[3]));
            } else {
              at_st64(hl1 + (long)b * 512 + rowt1 * 4, pk4(pbh[0], pbh[1], pbh[2], pbh[3]));
              at_st64(hl1 + HB + (long)b * 512 + rowt1 * 4, pk4(pbl[0], pbl[1], pbl[2], pbl[3]));
            }
          }
        }
      }
      if (s < 255) arriveflag(flagsB, (unsigned)(s + 1));
      else arrivecnt(C_FIN);
    }
  }
  waitcnt_(C_FIN, NBLK);

  // ================= FC =================
  if (bid < 128 && wid == 0) {
    const int b = bid;
    const int j0 = l * 8;
    u64x2 vh, vl;
    if (RING) {
      vh = *(const u64x2*)(h1rhi + (255L * 128 + b) * 512 + j0);
      vl = *(const u64x2*)(h1rlo + (255L * 128 + b) * 512 + j0);
    } else {
      vh.x = at_ld64(hl1 + (long)b * 512 + j0);
      vh.y = at_ld64(hl1 + (long)b * 512 + j0 + 4);
      vl.x = at_ld64(hl1 + HB + (long)b * 512 + j0);
      vl.y = at_ld64(hl1 + HB + (long)b * 512 + j0 + 4);
    }
    s16x8 hhi = __builtin_bit_cast(s16x8, vh);
    s16x8 hlo = __builtin_bit_cast(s16x8, vl);
    float ssum = 0.f;
#pragma unroll
    for (int e = 0; e < 8; ++e) {
      int j = j0 + e;
      float hf = bf2f((u16)hhi[e]) + bf2f((u16)hlo[e]);
      unsigned hbu = at_ld32(h1bf32 + (long)b * 512 + j);
      ssum += hf * fcw[j] + __builtin_bit_cast(float, hbu) * fcw[512 + j];
    }
#pragma unroll
    for (int off = 32; off; off >>= 1) ssum += __shfl_down(ssum, off);
    if (l == 0) out[b] = ssum + fcb[0];
  }
}

extern "C" void kernel_launch(void* const* d_in, const int* in_sizes, int n_in,
                              void* d_out, int out_size, void* d_ws, size_t ws_size,
                              hipStream_t stream) {
  const float* x     = (const float*)d_in[0];
  const float* wih0f = (const float*)d_in[1];
  const float* whh0f = (const float*)d_in[2];
  const float* b0f   = (const float*)d_in[3];
  const float* wih0b = (const float*)d_in[4];
  const float* whh0b = (const float*)d_in[5];
  const float* b0b   = (const float*)d_in[6];
  const float* wih1f = (const float*)d_in[7];
  const float* whh1f = (const float*)d_in[8];
  const float* b1f   = (const float*)d_in[9];
  const float* wih1b = (const float*)d_in[10];
  const float* whh1b = (const float*)d_in[11];
  const float* b1b   = (const float*)d_in[12];
  const float* fcw   = (const float*)d_in[13];
  const float* fcb   = (const float*)d_in[14];
  float* out = (float*)d_out;

  char* p = (char*)d_ws;
  char* pstart = p;
  auto alloc = [&](size_t bytes) {
    char* r = p;
    p += (bytes + 255) & ~(size_t)255;
    return r;
  };
  // common
  u16* xpack   = (u16*)alloc(128L * 256 * 64 * 2);
  u16* wih0f_p = (u16*)alloc(128L * 2 * 2 * 512 * 2);
  u16* wih0b_p = (u16*)alloc(128L * 2 * 2 * 512 * 2);
  u16* whh0f_p = (u16*)alloc(128L * 16 * 2 * 512 * 2);
  u16* whh0b_p = (u16*)alloc(128L * 16 * 2 * 512 * 2);
  u16* wih1f_p = (u16*)alloc(128L * 32 * 2 * 512 * 2);
  u16* whh1f_p = (u16*)alloc(128L * 16 * 2 * 512 * 2);
  u16* wih1b_p = (u16*)alloc(128L * 32 * 2 * 512 * 2);
  u16* whh1b_p = (u16*)alloc(128L * 16 * 2 * 512 * 2);
  float* biasP = (float*)alloc(8192 * 4);
  u16* hl0     = (u16*)alloc(2L * 2 * 2 * HB * 2);
  u16* hl1     = (u16*)alloc(2L * 2 * HB * 2);
  float* h1bf32= (float*)alloc((long)HB * 4);
  unsigned* flagsA = (unsigned*)alloc(256L * 64 * 4);
  unsigned* flagsB = (unsigned*)alloc(256L * 64 * 4);
  unsigned* cnt    = (unsigned*)alloc(128 * 4);
  u16* h0arch  = (u16*)alloc(256L * 128 * 1024 * 2);  // fallback also ring-hi space probe
  // ring extras
  size_t ring_need = (size_t)(p - pstart) + (256L * 128 * 1024 * 2) /*h0blo*/
                   + 2 * (256L * 128 * 512 * 2) /*h1rhi+h1rlo*/ + 1024;
  int ring = (ws_size >= ring_need) ? 1 : 0;
  u16* h0bhi = h0arch;  // reuse as bf16-hi ring in ring mode
  u16* h0blo = nullptr;
  u16* h1rhi = nullptr;
  u16* h1rlo = nullptr;
  if (ring) {
    h0blo = (u16*)alloc(256L * 128 * 1024 * 2);
    h1rhi = (u16*)alloc(256L * 128 * 512 * 2);
    h1rlo = (u16*)alloc(256L * 128 * 512 * 2);
  } else {
    h0blo = h0arch;  // unused in fallback; keep non-null
    h1rhi = h0arch;
    h1rlo = h0arch;
  }

  pack_w<true><<<64, 256, 0, stream>>>(wih0f, wih0f_p, 64);
  pack_w<true><<<64, 256, 0, stream>>>(wih0b, wih0b_p, 64);
  pack_w<false><<<512, 256, 0, stream>>>(whh0f, whh0f_p, 512);
  pack_w<false><<<512, 256, 0, stream>>>(whh0b, whh0b_p, 512);
  if (ring) {
    pack_w<false><<<1024, 256, 0, stream>>>(wih1f, wih1f_p, 1024);
    pack_w<false><<<1024, 256, 0, stream>>>(wih1b, wih1b_p, 1024);
  } else {
    pack_w<true><<<1024, 256, 0, stream>>>(wih1f, wih1f_p, 1024);
    pack_w<true><<<1024, 256, 0, stream>>>(wih1b, wih1b_p, 1024);
  }
  pack_w<false><<<512, 256, 0, stream>>>(whh1f, whh1f_p, 512);
  pack_w<false><<<512, 256, 0, stream>>>(whh1b, whh1b_p, 512);
  pack_x<<<8192, 256, 0, stream>>>(x, xpack);
  pack_bias<<<32, 256, 0, stream>>>(b0f, b0b, b1f, b1b, biasP);

  (void)hipMemsetAsync(flagsA, 0, 256L * 64 * 4, stream);
  (void)hipMemsetAsync(flagsB, 0, 256L * 64 * 4, stream);
  (void)hipMemsetAsync(cnt, 0, 128 * 4, stream);

  if (ring) {
    lstm_persist<1><<<NBLK, 512, 0, stream>>>(
        xpack, h0arch, h0bhi, h0blo, h1rhi, h1rlo,
        wih0f_p, wih0b_p, whh0f_p, whh0b_p,
        wih1f_p, whh1f_p, wih1b_p, whh1b_p,
        biasP, hl0, hl1, h1bf32, fcw, fcb, out, flagsA, flagsB, cnt);
  } else {
    lstm_persist<0><<<NBLK, 512, 0, stream>>>(
        xpack, h0arch, h0bhi, h0blo, h1rhi, h1rlo,
        wih0f_p, wih0b_p, whh0f_p, whh0b_p,
        wih1f_p, whh1f_p, wih1b_p, whh1b_p,
        biasP, hl0, hl1, h1bf32, fcw, fcb, out, flagsA, flagsB, cnt);
  }
}

// Round 12
// 3817.004 us; speedup vs baseline: 1.2997x; 1.2997x over previous
//
#include <hip/hip_runtime.h>

#define HB 65536  // 128*512 elements per [b][512] state plane
#define NBLK 256

typedef unsigned short u16;
typedef unsigned long long u64;
typedef __attribute__((ext_vector_type(8))) short bf16x8;
typedef __attribute__((ext_vector_type(8))) _Float16 f16x8;
typedef __attribute__((ext_vector_type(4))) float f32x4;
typedef __attribute__((ext_vector_type(2))) unsigned long long u64x2;
typedef __attribute__((ext_vector_type(8))) short s16x8;

#define MFMA_F16(a, b, c) __builtin_amdgcn_mfma_f32_16x16x32_f16(a, b, c, 0, 0, 0)
#define MFMA_BF16(a, b, c) __builtin_amdgcn_mfma_f32_16x16x32_bf16(a, b, c, 0, 0, 0)

__device__ __forceinline__ float fsig(float x) { return 1.f / (1.f + __expf(-x)); }
__device__ __forceinline__ float ftanh(float x) {
  float e = __expf(2.f * x);
  return 1.f - 2.f / (e + 1.f);
}
__device__ __forceinline__ u16 f2bf(float f) {
  unsigned u = __builtin_bit_cast(unsigned, f);
  return (u16)((u + 0x7FFFu + ((u >> 16) & 1)) >> 16);
}
__device__ __forceinline__ float bf2f(u16 h) {
  unsigned u = ((unsigned)h) << 16;
  return __builtin_bit_cast(float, u);
}
__device__ __forceinline__ u16 f2h(float f) {
  _Float16 h = (_Float16)f;
  return __builtin_bit_cast(u16, h);
}

// ---- coherence-point atomics (bypass non-coherent caches) ----
__device__ __forceinline__ u64 at_ld64(const void* p) {
  return __hip_atomic_load((const u64*)p, __ATOMIC_RELAXED, __HIP_MEMORY_SCOPE_AGENT);
}
__device__ __forceinline__ void at_st64(void* p, u64 v) {
  __hip_atomic_store((u64*)p, v, __ATOMIC_RELAXED, __HIP_MEMORY_SCOPE_AGENT);
}
__device__ __forceinline__ unsigned at_ld32(const void* p) {
  return __hip_atomic_load((const unsigned*)p, __ATOMIC_RELAXED, __HIP_MEMORY_SCOPE_AGENT);
}
__device__ __forceinline__ void at_st32(void* p, unsigned v) {
  __hip_atomic_store((unsigned*)p, v, __ATOMIC_RELAXED, __HIP_MEMORY_SCOPE_AGENT);
}
__device__ __forceinline__ u64 pk4(u16 a, u16 b, u16 c, u16 d) {
  return (u64)a | ((u64)b << 16) | ((u64)c << 32) | ((u64)d << 48);
}
__device__ __forceinline__ u64 pkf2(float a, float b) {
  return (u64)__builtin_bit_cast(unsigned, a) | ((u64)__builtin_bit_cast(unsigned, b) << 32);
}

// ---- pack weights [2048][K] fp32 -> fragment-major hi/lo ----
template <bool F16>
__global__ void pack_w(const float* __restrict__ W, u16* __restrict__ dst, int K) {
  int NKT = K >> 5;
  long gid = (long)blockIdx.x * 256 + threadIdx.x;
  long total = (long)128 * NKT * 64;
  if (gid >= total) return;
  int lane = gid & 63;
  int kt = (gid >> 6) % NKT;
  int rt = (gid >> 6) / NKT;
  int r = lane & 15;
  int grow = (r >> 2) * 512 + rt * 4 + (r & 3);
  int k0 = kt * 32 + (lane >> 4) * 8;
  long base = ((long)(rt * NKT + kt) * 2) * 512 + lane * 8;
#pragma unroll
  for (int e = 0; e < 8; ++e) {
    float w = W[(long)grow * K + k0 + e];
    u16 hi, lo;
    if (F16) {
      _Float16 h = (_Float16)w;
      hi = __builtin_bit_cast(u16, h);
      _Float16 l2 = (_Float16)(w - (float)h);
      lo = __builtin_bit_cast(u16, l2);
    } else {
      hi = f2bf(w);
      lo = f2bf(w - bf2f(hi));
    }
    dst[base + e] = hi;
    dst[base + 512 + e] = lo;
  }
}

__global__ void pack_x(const float* __restrict__ x, u16* __restrict__ xp) {
  long gid = (long)blockIdx.x * 256 + threadIdx.x;
  if (gid >= 128L * 256 * 64) return;
  int k = gid & 63;
  long bt = gid >> 6;
  int t = bt & 255;
  int b = bt >> 8;
  xp[((long)t * 128 + b) * 64 + k] = f2h(x[((long)b * 256 + t) * 64 + k]);
}

__global__ void pack_bias(const float* __restrict__ b0f, const float* __restrict__ b0b,
                          const float* __restrict__ b1f, const float* __restrict__ b1b,
                          float* __restrict__ bp) {
  int gid = blockIdx.x * 256 + threadIdx.x;
  if (gid >= 8192) return;
  int src = gid >> 11;
  int idx = gid & 2047;
  int rt = idx >> 4, rr = idx & 15;
  int grow = (rr >> 2) * 512 + rt * 4 + (rr & 3);
  const float* B = (src == 0) ? b0f : (src == 1) ? b0b : (src == 2) ? b1f : b1b;
  bp[gid] = B[grow];
}

#define C_TRANS 0
#define C_FIN 64

// ---- persistent kernel: weights live in VGPRs across the step loops ----
__global__ __launch_bounds__(512, 2) void lstm_persist(
    const u16* __restrict__ xpack, u16* __restrict__ h0arch,
    const u16* __restrict__ wih0f_p, const u16* __restrict__ wih0b_p,
    const u16* __restrict__ whh0f_p, const u16* __restrict__ whh0b_p,
    const u16* __restrict__ wih1f_p, const u16* __restrict__ whh1f_p,
    const u16* __restrict__ wih1b_p, const u16* __restrict__ whh1b_p,
    const float* __restrict__ biasP,
    u16* __restrict__ hl0, u16* __restrict__ hl1,
    float* __restrict__ h1bf32,
    const float* __restrict__ fcw, const float* __restrict__ fcb,
    float* __restrict__ out,
    unsigned* __restrict__ flagsA, unsigned* __restrict__ flagsB,
    unsigned* __restrict__ cnt) {
  const int bid = blockIdx.x;
  const int xcd = bid & 7, slot = bid >> 3;
  const int tid = threadIdx.x;
  const int wid = tid >> 6, l = tid & 63;
  const int c = l & 15, q = l >> 4;

  __shared__ __align__(16) char smem[65536];       // h staging [hi 32K | lo 32K]
  __shared__ __align__(16) f32x4 shacc[8][2][64];  // 16 KB K-slice reduce

  const f32x4 fz = {0.f, 0.f, 0.f, 0.f};

  auto arriveflag = [&](unsigned* fl, unsigned gen) {
    asm volatile("s_waitcnt vmcnt(0)" ::: "memory");  // sc1 data stores at L3
    __syncthreads();
    if (tid == 0) at_st32(fl + (long)bid * 64, gen);
  };
  auto waitflags = [&](const unsigned* fl, int base, int nmem, unsigned gen) {
    if (wid == 0) {
      unsigned f;
      do {
        f = (l < nmem) ? at_ld32(fl + (long)(base + l) * 64) : gen;
      } while (__ballot(f < gen));
    }
    __syncthreads();
  };
  auto arrivecnt = [&](int idx) {
    asm volatile("s_waitcnt vmcnt(0)" ::: "memory");
    __syncthreads();
    if (tid == 0)
      __hip_atomic_fetch_add(cnt + idx, 1u, __ATOMIC_RELAXED, __HIP_MEMORY_SCOPE_AGENT);
  };
  auto waitcnt_ = [&](int idx, unsigned tgt) {
    if (tid == 0) {
      while (at_ld32(cnt + idx) < tgt) __builtin_amdgcn_s_sleep(1);
    }
    __syncthreads();
  };

  // ================= Phase L0: 256 steps, both dirs, 8 groups of 32 =================
  {
    const int d = slot >> 4;
    const int bg = (slot >> 2) & 3;
    const int gbase = d * 128 + bg * 32;
    const int ug = xcd * 4 + (slot & 3);
    const int rowt = ug * 4 + (wid >> 1);  // wave owns this rowt fully
    const int kh = wid & 1;                // K half (whh: 8 kt; x: 1 kt)
    const u16* wxp = d ? wih0b_p : wih0f_p;
    const u16* whp = d ? whh0b_p : whh0f_p;
    const int b0e = bg * 32 + kh * 16;     // epilogue fragment (rowt, btl = kh)
    const float* bp = biasP + ((long)d * 128 + rowt) * 16 + q * 4;

    // ---- preload weights into registers (once) ----
    f16x8 wxh, wxl;
    {
      const u16* a = wxp + ((long)(rowt * 2 + kh) * 2) * 512 + l * 8;
      wxh = *(const f16x8*)a;
      wxl = *(const f16x8*)(a + 512);
    }
    bf16x8 whh_r[8], whl_r[8];
#pragma unroll
    for (int j = 0; j < 8; ++j) {
      const u16* a = whp + ((long)(rowt * 16 + kh * 8 + j) * 2) * 512 + l * 8;
      whh_r[j] = *(const bf16x8*)a;
      whl_r[j] = *(const bf16x8*)(a + 512);
    }

    // swizzle: XOR applied AFTER combining kt bits (bit-6 collision — r11 bug fixed)
    const int sw = (c & 7) << 4;
    const int cq0 = (c << 10) | (q << 4);
    const int cq1 = ((16 + c) << 10) | (q << 4);

    float c_reg[4] = {0.f, 0.f, 0.f, 0.f};
    for (int s = 0; s < 256; ++s) {
      const int t = d ? 255 - s : s;
      const int par = s & 1;
      f32x4 acc0 = fz, acc1 = fz;
      // x-projection from registers (B from L2 xpack)
      {
        const u16* xb = xpack + ((long)t * 128 + bg * 32 + c) * 64 + kh * 32 + q * 8;
        f16x8 bx0 = *(const f16x8*)xb;
        f16x8 bx1 = *(const f16x8*)(xb + 16 * 64);
        acc0 = MFMA_F16(wxh, bx0, acc0);
        acc0 = MFMA_F16(wxl, bx0, acc0);
        acc1 = MFMA_F16(wxh, bx1, acc1);
        acc1 = MFMA_F16(wxl, bx1, acc1);
      }
      if (s) {
        waitflags(flagsA, gbase, 32, s);
        const u16* hp_hi = hl0 + ((long)(par * 2 + d) * 2) * HB;
        const u16* hp_lo = hp_hi + HB;
#pragma unroll
        for (int i = 0; i < 8; ++i) {
          int m = tid + (i << 9);
          int pl = m >> 11, r = m & 2047;
          int b = r >> 6, k16 = r & 63;
          const u16* src = (pl ? hp_lo : hp_hi) + (long)(bg * 32 + b) * 512 + k16 * 8;
          u64x2 v;
          v.x = at_ld64(src);
          v.y = at_ld64(src + 4);
          int dst = pl * 32768 + (((b << 10) | (k16 << 4)) ^ ((b & 7) << 4));
          *(u64x2*)(smem + dst) = v;
        }
        __syncthreads();
#pragma unroll
        for (int j = 0; j < 8; ++j) {
          const int kt = kh * 8 + j;
          const int b0a = (cq0 | (kt << 6)) ^ sw;
          const int b1a = (cq1 | (kt << 6)) ^ sw;
          bf16x8 bhi0 = *(const bf16x8*)(smem + b0a);
          bf16x8 blo0 = *(const bf16x8*)(smem + 32768 + b0a);
          bf16x8 bhi1 = *(const bf16x8*)(smem + b1a);
          bf16x8 blo1 = *(const bf16x8*)(smem + 32768 + b1a);
          acc0 = MFMA_BF16(whh_r[j], bhi0, acc0);
          acc0 = MFMA_BF16(whl_r[j], bhi0, acc0);
          acc0 = MFMA_BF16(whh_r[j], blo0, acc0);
          acc1 = MFMA_BF16(whh_r[j], bhi1, acc1);
          acc1 = MFMA_BF16(whl_r[j], bhi1, acc1);
          acc1 = MFMA_BF16(whh_r[j], blo1, acc1);
        }
      }
      // K-slice reduce across kh pairs
      shacc[wid][0][l] = acc0;
      shacc[wid][1][l] = acc1;
      __syncthreads();
      {
        const int pr = (wid >> 1) * 2;
        const int bo = wid & 1;
        f32x4 tot = shacc[pr][bo][l] + shacc[pr + 1][bo][l];
        float pre[4];
#pragma unroll
        for (int i = 0; i < 4; ++i) pre[i] = tot[i] + bp[i];
        const int par_w = par ^ 1;
        u16* hn_hi = hl0 + ((long)(par_w * 2 + d) * 2) * HB;
        u16* hn_lo = hn_hi + HB;
        const int b = b0e + c;
        u16 pbh[4], pbl[4], pf[4];
#pragma unroll
        for (int i = 0; i < 4; ++i) {
          float gI = __shfl(pre[i], c);
          float gF = __shfl(pre[i], c + 16);
          float gG = __shfl(pre[i], c + 32);
          float gO = __shfl(pre[i], c + 48);
          float cn = fsig(gF) * c_reg[i] + fsig(gI) * ftanh(gG);
          c_reg[i] = cn;
          float hv = fsig(gO) * ftanh(cn);
          u16 hh = f2bf(hv);
          pbh[i] = hh;
          pbl[i] = f2bf(hv - bf2f(hh));
          pf[i] = f2h(hv);
        }
        if (q == 0) {
          if (s < 255) {
            at_st64(hn_hi + (long)b * 512 + rowt * 4, pk4(pbh[0], pbh[1], pbh[2], pbh[3]));
            at_st64(hn_lo + (long)b * 512 + rowt * 4, pk4(pbl[0], pbl[1], pbl[2], pbl[3]));
          }
          at_st64(h0arch + ((long)t * 128 + b) * 1024 + d * 512 + rowt * 4,
                  pk4(pf[0], pf[1], pf[2], pf[3]));
        }
      }
      if (s < 255) arriveflag(flagsA, (unsigned)(s + 1));
      else arrivecnt(C_TRANS);
    }
  }
  waitcnt_(C_TRANS, NBLK);
  __threadfence();  // one-time inv: plain h0arch reads below see fresh data
  __syncthreads();

  // ================= Phase L1B: single step t=255 (zero state) =================
  {
    const int ug1 = xcd * 8 + (slot & 7);
    const int bg1 = slot >> 3;
    const int rl1 = (wid >> 1) & 1;
    const int btl1 = wid & 1;
    const int kh = wid >> 2;
    const int rowt1 = ug1 * 2 + rl1;
    const int b01 = bg1 * 32 + btl1 * 16;
    f32x4 a0 = fz, a1 = fz;
    const u16* bbase = h0arch + (255L * 128 + b01 + c) * 1024 + q * 8;
#pragma unroll
    for (int kk = 0; kk < 16; ++kk) {
      int kt = kh * 16 + kk;
      const u16* a = wih1b_p + ((long)(rowt1 * 32 + kt) * 2) * 512 + l * 8;
      f16x8 ahi = *(const f16x8*)a;
      f16x8 alo = *(const f16x8*)(a + 512);
      f16x8 bx = *(const f16x8*)(bbase + kt * 32);
      f32x4& t0 = (kk & 1) ? a1 : a0;
      t0 = MFMA_F16(ahi, bx, t0);
      t0 = MFMA_F16(alo, bx, t0);
    }
    f32x4 acc = a0 + a1;
    shacc[wid][0][l] = acc;
    __syncthreads();
    if (wid < 4) {
      f32x4 tot = shacc[wid][0][l] + shacc[wid + 4][0][l];
      const float* bp1 = biasP + (3L * 128 + rowt1) * 16 + q * 4;
      float pre[4];
#pragma unroll
      for (int i = 0; i < 4; ++i) pre[i] = tot[i] + bp1[i];
      const int b = b01 + c;
      float hv[4];
#pragma unroll
      for (int i = 0; i < 4; ++i) {
        float gI = __shfl(pre[i], c);
        float gG = __shfl(pre[i], c + 32);
        float gO = __shfl(pre[i], c + 48);
        float cn = fsig(gI) * ftanh(gG);
        hv[i] = fsig(gO) * ftanh(cn);
      }
      if (q == 0) {
        at_st64((u16*)(h1bf32 + (long)b * 512 + rowt1 * 4), pkf2(hv[0], hv[1]));
        at_st64((u16*)(h1bf32 + (long)b * 512 + rowt1 * 4 + 2), pkf2(hv[2], hv[3]));
      }
    }
    __syncthreads();
  }

  // ================= Phase L1F: 256 steps, 4 groups of 64, weights in regs ==========
  {
    const int ug1 = xcd * 8 + (slot & 7);
    const int bg1 = slot >> 3;
    const int g1base = bg1 * 64;
    const int rl1 = wid & 1;
    const int kh1 = wid >> 1;  // 0..3
    const int rowt1 = ug1 * 2 + rl1;

    // ---- preload weights (once) ----
    f16x8 w1h[8], w1l[8];
#pragma unroll
    for (int j = 0; j < 8; ++j) {
      const u16* a = wih1f_p + ((long)(rowt1 * 32 + kh1 * 8 + j) * 2) * 512 + l * 8;
      w1h[j] = *(const f16x8*)a;
      w1l[j] = *(const f16x8*)(a + 512);
    }
    bf16x8 v1h[4], v1l[4];
#pragma unroll
    for (int j = 0; j < 4; ++j) {
      const u16* a = whh1f_p + ((long)(rowt1 * 16 + kh1 * 4 + j) * 2) * 512 + l * 8;
      v1h[j] = *(const bf16x8*)a;
      v1l[j] = *(const bf16x8*)(a + 512);
    }

    const int sw = (c & 7) << 4;
    const int cq0 = (c << 10) | (q << 4);
    const int cq1 = ((16 + c) << 10) | (q << 4);
    // epilogue ownership (wid<4): rowt_o = ug1*2 + (wid&1), btl_o = wid>>1
    const int rl_o = wid & 1;
    const int bt_o = wid >> 1;
    const int rowt_o = ug1 * 2 + rl_o;
    const float* bp1 = biasP + (2L * 128 + rowt_o) * 16 + q * 4;

    float c_reg[4] = {0.f, 0.f, 0.f, 0.f};
    for (int s = 0; s < 256; ++s) {
      const int par = s & 1;
      f32x4 acc0 = fz, acc1 = fz;
      // h0 projection from registers (B from h0arch, plain cached)
      {
        const u16* hb = h0arch + ((long)s * 128 + bg1 * 32 + c) * 1024 + q * 8;
#pragma unroll
        for (int j = 0; j < 8; ++j) {
          const int kt = kh1 * 8 + j;
          f16x8 bx0 = *(const f16x8*)(hb + kt * 32);
          f16x8 bx1 = *(const f16x8*)(hb + 16 * 1024 + kt * 32);
          acc0 = MFMA_F16(w1h[j], bx0, acc0);
          acc0 = MFMA_F16(w1l[j], bx0, acc0);
          acc1 = MFMA_F16(w1h[j], bx1, acc1);
          acc1 = MFMA_F16(w1l[j], bx1, acc1);
        }
      }
      if (s) {
        waitflags(flagsB, g1base, 64, s);
        const u16* hp_hi = hl1 + (long)(par * 2) * HB;
        const u16* hp_lo = hp_hi + HB;
#pragma unroll
        for (int i = 0; i < 8; ++i) {
          int m = tid + (i << 9);
          int pl = m >> 11, r = m & 2047;
          int b = r >> 6, k16 = r & 63;
          const u16* src = (pl ? hp_lo : hp_hi) + (long)(bg1 * 32 + b) * 512 + k16 * 8;
          u64x2 v;
          v.x = at_ld64(src);
          v.y = at_ld64(src + 4);
          int dst = pl * 32768 + (((b << 10) | (k16 << 4)) ^ ((b & 7) << 4));
          *(u64x2*)(smem + dst) = v;
        }
        __syncthreads();
#pragma unroll
        for (int j = 0; j < 4; ++j) {
          const int kt = kh1 * 4 + j;
          const int b0a = (cq0 | (kt << 6)) ^ sw;
          const int b1a = (cq1 | (kt << 6)) ^ sw;
          bf16x8 bhi0 = *(const bf16x8*)(smem + b0a);
          bf16x8 blo0 = *(const bf16x8*)(smem + 32768 + b0a);
          bf16x8 bhi1 = *(const bf16x8*)(smem + b1a);
          bf16x8 blo1 = *(const bf16x8*)(smem + 32768 + b1a);
          acc0 = MFMA_BF16(v1h[j], bhi0, acc0);
          acc0 = MFMA_BF16(v1l[j], bhi0, acc0);
          acc0 = MFMA_BF16(v1h[j], blo0, acc0);
          acc1 = MFMA_BF16(v1h[j], bhi1, acc1);
          acc1 = MFMA_BF16(v1l[j], bhi1, acc1);
          acc1 = MFMA_BF16(v1h[j], blo1, acc1);
        }
      }
      // K-slice reduce across 4 kh waves
      shacc[wid][0][l] = acc0;
      shacc[wid][1][l] = acc1;
      __syncthreads();
      if (wid < 4) {
        f32x4 tot = shacc[rl_o][bt_o][l] + shacc[2 + rl_o][bt_o][l] +
                    shacc[4 + rl_o][bt_o][l] + shacc[6 + rl_o][bt_o][l];
        float pre[4];
#pragma unroll
        for (int i = 0; i < 4; ++i) pre[i] = tot[i] + bp1[i];
        const int par_w = par ^ 1;
        u16* hn_hi = hl1 + (long)(par_w * 2) * HB;
        u16* hn_lo = hn_hi + HB;
        const int b = bg1 * 32 + bt_o * 16 + c;
        u16 pbh[4], pbl[4];
#pragma unroll
        for (int i = 0; i < 4; ++i) {
          float gI = __shfl(pre[i], c);
          float gF = __shfl(pre[i], c + 16);
          float gG = __shfl(pre[i], c + 32);
          float gO = __shfl(pre[i], c + 48);
          float cn = fsig(gF) * c_reg[i] + fsig(gI) * ftanh(gG);
          c_reg[i] = cn;
          float hv = fsig(gO) * ftanh(cn);
          u16 hh = f2bf(hv);
          pbh[i] = hh;
          pbl[i] = f2bf(hv - bf2f(hh));
        }
        if (q == 0) {
          if (s < 255) {
            at_st64(hn_hi + (long)b * 512 + rowt_o * 4, pk4(pbh[0], pbh[1], pbh[2], pbh[3]));
            at_st64(hn_lo + (long)b * 512 + rowt_o * 4, pk4(pbl[0], pbl[1], pbl[2], pbl[3]));
          } else {  // final h -> parity-0 plane for FC
            at_st64(hl1 + (long)b * 512 + rowt_o * 4, pk4(pbh[0], pbh[1], pbh[2], pbh[3]));
            at_st64(hl1 + HB + (long)b * 512 + rowt_o * 4, pk4(pbl[0], pbl[1], pbl[2], pbl[3]));
          }
        }
      }
      if (s < 255) arriveflag(flagsB, (unsigned)(s + 1));
      else arrivecnt(C_FIN);
    }
  }
  waitcnt_(C_FIN, NBLK);

  // ================= FC =================
  if (bid < 128 && wid == 0) {
    const int b = bid;
    const int j0 = l * 8;
    u64x2 vh, vl;
    vh.x = at_ld64(hl1 + (long)b * 512 + j0);
    vh.y = at_ld64(hl1 + (long)b * 512 + j0 + 4);
    vl.x = at_ld64(hl1 + HB + (long)b * 512 + j0);
    vl.y = at_ld64(hl1 + HB + (long)b * 512 + j0 + 4);
    s16x8 hhi = __builtin_bit_cast(s16x8, vh);
    s16x8 hlo = __builtin_bit_cast(s16x8, vl);
    float ssum = 0.f;
#pragma unroll
    for (int e = 0; e < 8; ++e) {
      int j = j0 + e;
      float hf = bf2f((u16)hhi[e]) + bf2f((u16)hlo[e]);
      unsigned hbu = at_ld32(h1bf32 + (long)b * 512 + j);
      ssum += hf * fcw[j] + __builtin_bit_cast(float, hbu) * fcw[512 + j];
    }
#pragma unroll
    for (int off = 32; off; off >>= 1) ssum += __shfl_down(ssum, off);
    if (l == 0) out[b] = ssum + fcb[0];
  }
}

extern "C" void kernel_launch(void* const* d_in, const int* in_sizes, int n_in,
                              void* d_out, int out_size, void* d_ws, size_t ws_size,
                              hipStream_t stream) {
  const float* x     = (const float*)d_in[0];
  const float* wih0f = (const float*)d_in[1];
  const float* whh0f = (const float*)d_in[2];
  const float* b0f   = (const float*)d_in[3];
  const float* wih0b = (const float*)d_in[4];
  const float* whh0b = (const float*)d_in[5];
  const float* b0b   = (const float*)d_in[6];
  const float* wih1f = (const float*)d_in[7];
  const float* whh1f = (const float*)d_in[8];
  const float* b1f   = (const float*)d_in[9];
  const float* wih1b = (const float*)d_in[10];
  const float* whh1b = (const float*)d_in[11];
  const float* b1b   = (const float*)d_in[12];
  const float* fcw   = (const float*)d_in[13];
  const float* fcb   = (const float*)d_in[14];
  float* out = (float*)d_out;

  char* p = (char*)d_ws;
  auto alloc = [&](size_t bytes) {
    char* r = p;
    p += (bytes + 255) & ~(size_t)255;
    return r;
  };
  u16* xpack   = (u16*)alloc(128L * 256 * 64 * 2);
  u16* wih0f_p = (u16*)alloc(128L * 2 * 2 * 512 * 2);
  u16* wih0b_p = (u16*)alloc(128L * 2 * 2 * 512 * 2);
  u16* whh0f_p = (u16*)alloc(128L * 16 * 2 * 512 * 2);
  u16* whh0b_p = (u16*)alloc(128L * 16 * 2 * 512 * 2);
  u16* wih1f_p = (u16*)alloc(128L * 32 * 2 * 512 * 2);
  u16* whh1f_p = (u16*)alloc(128L * 16 * 2 * 512 * 2);
  u16* wih1b_p = (u16*)alloc(128L * 32 * 2 * 512 * 2);
  u16* whh1b_p = (u16*)alloc(128L * 16 * 2 * 512 * 2);
  float* biasP = (float*)alloc(8192 * 4);
  u16* hl0     = (u16*)alloc(2L * 2 * 2 * HB * 2);
  u16* hl1     = (u16*)alloc(2L * 2 * HB * 2);
  float* h1bf32= (float*)alloc((long)HB * 4);
  unsigned* flagsA = (unsigned*)alloc(256L * 64 * 4);
  unsigned* flagsB = (unsigned*)alloc(256L * 64 * 4);
  unsigned* cnt    = (unsigned*)alloc(128 * 4);
  u16* h0arch  = (u16*)alloc(256L * 128 * 1024 * 2);

  pack_w<true><<<64, 256, 0, stream>>>(wih0f, wih0f_p, 64);
  pack_w<true><<<64, 256, 0, stream>>>(wih0b, wih0b_p, 64);
  pack_w<false><<<512, 256, 0, stream>>>(whh0f, whh0f_p, 512);
  pack_w<false><<<512, 256, 0, stream>>>(whh0b, whh0b_p, 512);
  pack_w<true><<<1024, 256, 0, stream>>>(wih1f, wih1f_p, 1024);
  pack_w<true><<<1024, 256, 0, stream>>>(wih1b, wih1b_p, 1024);
  pack_w<false><<<512, 256, 0, stream>>>(whh1f, whh1f_p, 512);
  pack_w<false><<<512, 256, 0, stream>>>(whh1b, whh1b_p, 512);
  pack_x<<<8192, 256, 0, stream>>>(x, xpack);
  pack_bias<<<32, 256, 0, stream>>>(b0f, b0b, b1f, b1b, biasP);

  (void)hipMemsetAsync(flagsA, 0, 256L * 64 * 4, stream);
  (void)hipMemsetAsync(flagsB, 0, 256L * 64 * 4, stream);
  (void)hipMemsetAsync(cnt, 0, 128 * 4, stream);

  lstm_persist<<<NBLK, 512, 0, stream>>>(
      xpack, h0arch,
      wih0f_p, wih0b_p, whh0f_p, whh0b_p,
      wih1f_p, whh1f_p, wih1b_p, whh1b_p,
      biasP, hl0, hl1, h1bf32,
      fcw, fcb, out, flagsA, flagsB, cnt);
}

// Round 13
// 3124.586 us; speedup vs baseline: 1.5877x; 1.2216x over previous
//
#include <hip/hip_runtime.h>

#define NBLK 256
#define PLANE 131072  // u16 elems per interleaved h plane: 128 b x (512 hi + 512 lo)

typedef unsigned short u16;
typedef unsigned long long u64;
typedef __attribute__((ext_vector_type(8))) short bf16x8;
typedef __attribute__((ext_vector_type(8))) _Float16 f16x8;
typedef __attribute__((ext_vector_type(4))) float f32x4;
typedef __attribute__((ext_vector_type(2))) unsigned long long u64x2;

#define MFMA_F16(a, b, c) __builtin_amdgcn_mfma_f32_16x16x32_f16(a, b, c, 0, 0, 0)
#define MFMA_BF16(a, b, c) __builtin_amdgcn_mfma_f32_16x16x32_bf16(a, b, c, 0, 0, 0)

__device__ __forceinline__ float fsig(float x) { return 1.f / (1.f + __expf(-x)); }
__device__ __forceinline__ float ftanh(float x) {
  float e = __expf(2.f * x);
  return 1.f - 2.f / (e + 1.f);
}
__device__ __forceinline__ u16 f2bf(float f) {
  unsigned u = __builtin_bit_cast(unsigned, f);
  return (u16)((u + 0x7FFFu + ((u >> 16) & 1)) >> 16);
}
__device__ __forceinline__ float bf2f(u16 h) {
  unsigned u = ((unsigned)h) << 16;
  return __builtin_bit_cast(float, u);
}
__device__ __forceinline__ u16 f2h(float f) {
  _Float16 h = (_Float16)f;
  return __builtin_bit_cast(u16, h);
}

__device__ __forceinline__ u64 at_ld64(const void* p) {
  return __hip_atomic_load((const u64*)p, __ATOMIC_RELAXED, __HIP_MEMORY_SCOPE_AGENT);
}
__device__ __forceinline__ void at_st64(void* p, u64 v) {
  __hip_atomic_store((u64*)p, v, __ATOMIC_RELAXED, __HIP_MEMORY_SCOPE_AGENT);
}
__device__ __forceinline__ unsigned at_ld32(const void* p) {
  return __hip_atomic_load((const unsigned*)p, __ATOMIC_RELAXED, __HIP_MEMORY_SCOPE_AGENT);
}
__device__ __forceinline__ void at_st32(void* p, unsigned v) {
  __hip_atomic_store((unsigned*)p, v, __ATOMIC_RELAXED, __HIP_MEMORY_SCOPE_AGENT);
}
__device__ __forceinline__ u64 pk4(u16 a, u16 b, u16 c, u16 d) {
  return (u64)a | ((u64)b << 16) | ((u64)c << 32) | ((u64)d << 48);
}
__device__ __forceinline__ u64 pkf2(float a, float b) {
  return (u64)__builtin_bit_cast(unsigned, a) | ((u64)__builtin_bit_cast(unsigned, b) << 32);
}
// 16B coherence-point ops (sc0 sc1 = bypass L1+L2, service at L3)
__device__ __forceinline__ void st128_cp(u16* p, u64x2 v) {
  asm volatile("global_store_dwordx4 %0, %1, off sc0 sc1" :: "v"(p), "v"(v) : "memory");
}

// ---- pack weights [2048][K] fp32 -> fragment-major hi/lo ----
template <bool F16>
__global__ void pack_w(const float* __restrict__ W, u16* __restrict__ dst, int K) {
  int NKT = K >> 5;
  long gid = (long)blockIdx.x * 256 + threadIdx.x;
  long total = (long)128 * NKT * 64;
  if (gid >= total) return;
  int lane = gid & 63;
  int kt = (gid >> 6) % NKT;
  int rt = (gid >> 6) / NKT;
  int r = lane & 15;
  int grow = (r >> 2) * 512 + rt * 4 + (r & 3);
  int k0 = kt * 32 + (lane >> 4) * 8;
  long base = ((long)(rt * NKT + kt) * 2) * 512 + lane * 8;
#pragma unroll
  for (int e = 0; e < 8; ++e) {
    float w = W[(long)grow * K + k0 + e];
    u16 hi, lo;
    if (F16) {
      _Float16 h = (_Float16)w;
      hi = __builtin_bit_cast(u16, h);
      _Float16 l2 = (_Float16)(w - (float)h);
      lo = __builtin_bit_cast(u16, l2);
    } else {
      hi = f2bf(w);
      lo = f2bf(w - bf2f(hi));
    }
    dst[base + e] = hi;
    dst[base + 512 + e] = lo;
  }
}

__global__ void pack_x(const float* __restrict__ x, u16* __restrict__ xp) {
  long gid = (long)blockIdx.x * 256 + threadIdx.x;
  if (gid >= 128L * 256 * 64) return;
  int k = gid & 63;
  long bt = gid >> 6;
  int t = bt & 255;
  int b = bt >> 8;
  xp[((long)t * 128 + b) * 64 + k] = f2h(x[((long)b * 256 + t) * 64 + k]);
}

__global__ void pack_bias(const float* __restrict__ b0f, const float* __restrict__ b0b,
                          const float* __restrict__ b1f, const float* __restrict__ b1b,
                          float* __restrict__ bp) {
  int gid = blockIdx.x * 256 + threadIdx.x;
  if (gid >= 8192) return;
  int src = gid >> 11;
  int idx = gid & 2047;
  int rt = idx >> 4, rr = idx & 15;
  int grow = (rr >> 2) * 512 + rt * 4 + (rr & 3);
  const float* B = (src == 0) ? b0f : (src == 1) ? b0b : (src == 2) ? b1f : b1b;
  bp[gid] = B[grow];
}

#define C_TRANS 0
#define C_FIN 64

// ---- persistent kernel: VGPR-resident weights + 16B interleaved h exchange ----
__global__ __launch_bounds__(512, 2) void lstm_persist(
    const u16* __restrict__ xpack, u16* __restrict__ h0arch,
    const u16* __restrict__ wih0f_p, const u16* __restrict__ wih0b_p,
    const u16* __restrict__ whh0f_p, const u16* __restrict__ whh0b_p,
    const u16* __restrict__ wih1f_p, const u16* __restrict__ whh1f_p,
    const u16* __restrict__ wih1b_p, const u16* __restrict__ whh1b_p,
    const float* __restrict__ biasP,
    u16* __restrict__ hl0, u16* __restrict__ hl1,
    float* __restrict__ h1bf32,
    const float* __restrict__ fcw, const float* __restrict__ fcb,
    float* __restrict__ out,
    unsigned* __restrict__ flagsA, unsigned* __restrict__ flagsB,
    unsigned* __restrict__ cnt) {
  const int bid = blockIdx.x;
  const int xcd = bid & 7, slot = bid >> 3;
  const int tid = threadIdx.x;
  const int wid = tid >> 6, l = tid & 63;
  const int c = l & 15, q = l >> 4;

  __shared__ __align__(16) char smem[65536];       // h staging [hi 32K | lo 32K]
  __shared__ __align__(16) f32x4 shacc[8][2][64];  // 16 KB K-slice reduce

  const f32x4 fz = {0.f, 0.f, 0.f, 0.f};

  auto arriveflag = [&](unsigned* fl, unsigned gen) {
    asm volatile("s_waitcnt vmcnt(0)" ::: "memory");
    __syncthreads();
    if (tid == 0) at_st32(fl + (long)bid * 64, gen);
  };
  auto waitflags = [&](const unsigned* fl, int base, int nmem, unsigned gen) {
    if (wid == 0) {
      unsigned f;
      do {
        f = (l < nmem) ? at_ld32(fl + (long)(base + l) * 64) : gen;
      } while (__ballot(f < gen));
    }
    __syncthreads();
  };
  auto arrivecnt = [&](int idx) {
    asm volatile("s_waitcnt vmcnt(0)" ::: "memory");
    __syncthreads();
    if (tid == 0)
      __hip_atomic_fetch_add(cnt + idx, 1u, __ATOMIC_RELAXED, __HIP_MEMORY_SCOPE_AGENT);
  };
  auto waitcnt_ = [&](int idx, unsigned tgt) {
    if (tid == 0) {
      while (at_ld32(cnt + idx) < tgt) __builtin_amdgcn_s_sleep(1);
    }
    __syncthreads();
  };
  // stage 32 batches: 8x 16B sc1 loads, de-interleave to smem hi/lo (r12 layout)
  auto stage16 = [&](const u16* plane, int b0blk) {
    u64x2 vv[8];
#pragma unroll
    for (int i = 0; i < 8; ++i) {
      int m = tid + (i << 9);
      int b = m >> 7, cb = m & 127;
      const u16* src = plane + ((long)(b0blk + b) << 10) + (cb << 3);
      asm volatile("global_load_dwordx4 %0, %1, off sc0 sc1"
                   : "=v"(vv[i]) : "v"(src) : "memory");
    }
    asm volatile("s_waitcnt vmcnt(0)" ::: "memory");
    __builtin_amdgcn_sched_barrier(0);
#pragma unroll
    for (int i = 0; i < 8; ++i) {
      int m = tid + (i << 9);
      int b = m >> 7, cb = m & 127;
      int ahi = ((b << 10) | (cb << 3)) ^ ((b & 7) << 4);
      *(u64*)(smem + ahi) = vv[i].x;
      *(u64*)(smem + 32768 + ahi) = vv[i].y;
    }
  };

  // ================= Phase L0: 256 steps, both dirs, 8 groups of 32 =================
  {
    const int d = slot >> 4;
    const int bg = (slot >> 2) & 3;
    const int gbase = d * 128 + bg * 32;
    const int ug = xcd * 4 + (slot & 3);
    const int rowt = ug * 4 + (wid >> 1);
    const int kh = wid & 1;
    const u16* wxp = d ? wih0b_p : wih0f_p;
    const u16* whp = d ? whh0b_p : whh0f_p;
    const int b0e = bg * 32 + kh * 16;
    const float* bp = biasP + ((long)d * 128 + rowt) * 16 + q * 4;

    // preload weights into registers
    f16x8 wxh, wxl;
    {
      const u16* a = wxp + ((long)(rowt * 2 + kh) * 2) * 512 + l * 8;
      wxh = *(const f16x8*)a;
      wxl = *(const f16x8*)(a + 512);
    }
    bf16x8 whh_r[8], whl_r[8];
#pragma unroll
    for (int j = 0; j < 8; ++j) {
      const u16* a = whp + ((long)(rowt * 16 + kh * 8 + j) * 2) * 512 + l * 8;
      whh_r[j] = *(const bf16x8*)a;
      whl_r[j] = *(const bf16x8*)(a + 512);
    }

    const int sw = (c & 7) << 4;
    const int cq0 = (c << 10) | (q << 4);
    const int cq1 = ((16 + c) << 10) | (q << 4);

    float c_reg[4] = {0.f, 0.f, 0.f, 0.f};
    for (int s = 0; s < 256; ++s) {
      const int t = d ? 255 - s : s;
      const int par = s & 1;
      f32x4 acc0 = fz, acc1 = fz;
      {
        const u16* xb = xpack + ((long)t * 128 + bg * 32 + c) * 64 + kh * 32 + q * 8;
        f16x8 bx0 = *(const f16x8*)xb;
        f16x8 bx1 = *(const f16x8*)(xb + 16 * 64);
        acc0 = MFMA_F16(wxh, bx0, acc0);
        acc0 = MFMA_F16(wxl, bx0, acc0);
        acc1 = MFMA_F16(wxh, bx1, acc1);
        acc1 = MFMA_F16(wxl, bx1, acc1);
      }
      if (s) {
        waitflags(flagsA, gbase, 32, s);
        stage16(hl0 + (long)(par * 2 + d) * PLANE, bg * 32);
        __syncthreads();
#pragma unroll
        for (int j = 0; j < 8; ++j) {
          const int kt = kh * 8 + j;
          const int b0a = (cq0 | (kt << 6)) ^ sw;
          const int b1a = (cq1 | (kt << 6)) ^ sw;
          bf16x8 bhi0 = *(const bf16x8*)(smem + b0a);
          bf16x8 blo0 = *(const bf16x8*)(smem + 32768 + b0a);
          bf16x8 bhi1 = *(const bf16x8*)(smem + b1a);
          bf16x8 blo1 = *(const bf16x8*)(smem + 32768 + b1a);
          acc0 = MFMA_BF16(whh_r[j], bhi0, acc0);
          acc0 = MFMA_BF16(whl_r[j], bhi0, acc0);
          acc0 = MFMA_BF16(whh_r[j], blo0, acc0);
          acc1 = MFMA_BF16(whh_r[j], bhi1, acc1);
          acc1 = MFMA_BF16(whl_r[j], bhi1, acc1);
          acc1 = MFMA_BF16(whh_r[j], blo1, acc1);
        }
      }
      shacc[wid][0][l] = acc0;
      shacc[wid][1][l] = acc1;
      __syncthreads();
      {
        const int pr = (wid >> 1) * 2;
        const int bo = wid & 1;
        f32x4 tot = shacc[pr][bo][l] + shacc[pr + 1][bo][l];
        float pre[4];
#pragma unroll
        for (int i = 0; i < 4; ++i) pre[i] = tot[i] + bp[i];
        const int par_w = par ^ 1;
        u16* hn = hl0 + (long)(par_w * 2 + d) * PLANE;
        const int b = b0e + c;
        u16 pbh[4], pbl[4], pf[4];
#pragma unroll
        for (int i = 0; i < 4; ++i) {
          float gI = __shfl(pre[i], c);
          float gF = __shfl(pre[i], c + 16);
          float gG = __shfl(pre[i], c + 32);
          float gO = __shfl(pre[i], c + 48);
          float cn = fsig(gF) * c_reg[i] + fsig(gI) * ftanh(gG);
          c_reg[i] = cn;
          float hv = fsig(gO) * ftanh(cn);
          u16 hh = f2bf(hv);
          pbh[i] = hh;
          pbl[i] = f2bf(hv - bf2f(hh));
          pf[i] = f2h(hv);
        }
        if (q == 0) {
          if (s < 255) {
            u64x2 pv;
            pv.x = pk4(pbh[0], pbh[1], pbh[2], pbh[3]);
            pv.y = pk4(pbl[0], pbl[1], pbl[2], pbl[3]);
            st128_cp(hn + ((long)b << 10) + rowt * 8, pv);
          }
          at_st64(h0arch + ((long)t * 128 + b) * 1024 + d * 512 + rowt * 4,
                  pk4(pf[0], pf[1], pf[2], pf[3]));
        }
      }
      if (s < 255) arriveflag(flagsA, (unsigned)(s + 1));
      else arrivecnt(C_TRANS);
    }
  }
  waitcnt_(C_TRANS, NBLK);
  __threadfence();  // one-time inv: plain h0arch reads below see fresh data
  __syncthreads();

  // ================= Phase L1B: single step t=255 (zero state) =================
  {
    const int ug1 = xcd * 8 + (slot & 7);
    const int bg1 = slot >> 3;
    const int rl1 = (wid >> 1) & 1;
    const int btl1 = wid & 1;
    const int kh = wid >> 2;
    const int rowt1 = ug1 * 2 + rl1;
    const int b01 = bg1 * 32 + btl1 * 16;
    f32x4 a0 = fz, a1 = fz;
    const u16* bbase = h0arch + (255L * 128 + b01 + c) * 1024 + q * 8;
#pragma unroll
    for (int kk = 0; kk < 16; ++kk) {
      int kt = kh * 16 + kk;
      const u16* a = wih1b_p + ((long)(rowt1 * 32 + kt) * 2) * 512 + l * 8;
      f16x8 ahi = *(const f16x8*)a;
      f16x8 alo = *(const f16x8*)(a + 512);
      f16x8 bx = *(const f16x8*)(bbase + kt * 32);
      f32x4& t0 = (kk & 1) ? a1 : a0;
      t0 = MFMA_F16(ahi, bx, t0);
      t0 = MFMA_F16(alo, bx, t0);
    }
    f32x4 acc = a0 + a1;
    shacc[wid][0][l] = acc;
    __syncthreads();
    if (wid < 4) {
      f32x4 tot = shacc[wid][0][l] + shacc[wid + 4][0][l];
      const float* bp1 = biasP + (3L * 128 + rowt1) * 16 + q * 4;
      float pre[4];
#pragma unroll
      for (int i = 0; i < 4; ++i) pre[i] = tot[i] + bp1[i];
      const int b = b01 + c;
      float hv[4];
#pragma unroll
      for (int i = 0; i < 4; ++i) {
        float gI = __shfl(pre[i], c);
        float gG = __shfl(pre[i], c + 32);
        float gO = __shfl(pre[i], c + 48);
        float cn = fsig(gI) * ftanh(gG);
        hv[i] = fsig(gO) * ftanh(cn);
      }
      if (q == 0) {
        at_st64((u16*)(h1bf32 + (long)b * 512 + rowt1 * 4), pkf2(hv[0], hv[1]));
        at_st64((u16*)(h1bf32 + (long)b * 512 + rowt1 * 4 + 2), pkf2(hv[2], hv[3]));
      }
    }
    __syncthreads();
  }

  // ================= Phase L1F: 256 steps, 4 groups of 64, weights in regs ==========
  {
    const int ug1 = xcd * 8 + (slot & 7);
    const int bg1 = slot >> 3;
    const int g1base = bg1 * 64;
    const int rl1 = wid & 1;
    const int kh1 = wid >> 1;
    const int rowt1 = ug1 * 2 + rl1;

    f16x8 w1h[8], w1l[8];
#pragma unroll
    for (int j = 0; j < 8; ++j) {
      const u16* a = wih1f_p + ((long)(rowt1 * 32 + kh1 * 8 + j) * 2) * 512 + l * 8;
      w1h[j] = *(const f16x8*)a;
      w1l[j] = *(const f16x8*)(a + 512);
    }
    bf16x8 v1h[4], v1l[4];
#pragma unroll
    for (int j = 0; j < 4; ++j) {
      const u16* a = whh1f_p + ((long)(rowt1 * 16 + kh1 * 4 + j) * 2) * 512 + l * 8;
      v1h[j] = *(const bf16x8*)a;
      v1l[j] = *(const bf16x8*)(a + 512);
    }

    const int sw = (c & 7) << 4;
    const int cq0 = (c << 10) | (q << 4);
    const int cq1 = ((16 + c) << 10) | (q << 4);
    const int rl_o = wid & 1;
    const int bt_o = wid >> 1;
    const int rowt_o = ug1 * 2 + rl_o;
    const float* bp1 = biasP + (2L * 128 + rowt_o) * 16 + q * 4;

    float c_reg[4] = {0.f, 0.f, 0.f, 0.f};
    for (int s = 0; s < 256; ++s) {
      const int par = s & 1;
      f32x4 acc0 = fz, acc1 = fz;
      {
        const u16* hb = h0arch + ((long)s * 128 + bg1 * 32 + c) * 1024 + q * 8;
#pragma unroll
        for (int j = 0; j < 8; ++j) {
          const int kt = kh1 * 8 + j;
          f16x8 bx0 = *(const f16x8*)(hb + kt * 32);
          f16x8 bx1 = *(const f16x8*)(hb + 16 * 1024 + kt * 32);
          acc0 = MFMA_F16(w1h[j], bx0, acc0);
          acc0 = MFMA_F16(w1l[j], bx0, acc0);
          acc1 = MFMA_F16(w1h[j], bx1, acc1);
          acc1 = MFMA_F16(w1l[j], bx1, acc1);
        }
      }
      if (s) {
        waitflags(flagsB, g1base, 64, s);
        stage16(hl1 + (long)par * PLANE, bg1 * 32);
        __syncthreads();
#pragma unroll
        for (int j = 0; j < 4; ++j) {
          const int kt = kh1 * 4 + j;
          const int b0a = (cq0 | (kt << 6)) ^ sw;
          const int b1a = (cq1 | (kt << 6)) ^ sw;
          bf16x8 bhi0 = *(const bf16x8*)(smem + b0a);
          bf16x8 blo0 = *(const bf16x8*)(smem + 32768 + b0a);
          bf16x8 bhi1 = *(const bf16x8*)(smem + b1a);
          bf16x8 blo1 = *(const bf16x8*)(smem + 32768 + b1a);
          acc0 = MFMA_BF16(v1h[j], bhi0, acc0);
          acc0 = MFMA_BF16(v1l[j], bhi0, acc0);
          acc0 = MFMA_BF16(v1h[j], blo0, acc0);
          acc1 = MFMA_BF16(v1h[j], bhi1, acc1);
          acc1 = MFMA_BF16(v1l[j], bhi1, acc1);
          acc1 = MFMA_BF16(v1h[j], blo1, acc1);
        }
      }
      shacc[wid][0][l] = acc0;
      shacc[wid][1][l] = acc1;
      __syncthreads();
      if (wid < 4) {
        f32x4 tot = shacc[rl_o][bt_o][l] + shacc[2 + rl_o][bt_o][l] +
                    shacc[4 + rl_o][bt_o][l] + shacc[6 + rl_o][bt_o][l];
        float pre[4];
#pragma unroll
        for (int i = 0; i < 4; ++i) pre[i] = tot[i] + bp1[i];
        const int par_w = par ^ 1;
        u16* hn = hl1 + (long)par_w * PLANE;
        const int b = bg1 * 32 + bt_o * 16 + c;
        u16 pbh[4], pbl[4];
#pragma unroll
        for (int i = 0; i < 4; ++i) {
          float gI = __shfl(pre[i], c);
          float gF = __shfl(pre[i], c + 16);
          float gG = __shfl(pre[i], c + 32);
          float gO = __shfl(pre[i], c + 48);
          float cn = fsig(gF) * c_reg[i] + fsig(gI) * ftanh(gG);
          c_reg[i] = cn;
          float hv = fsig(gO) * ftanh(cn);
          u16 hh = f2bf(hv);
          pbh[i] = hh;
          pbl[i] = f2bf(hv - bf2f(hh));
        }
        if (q == 0) {
          u64x2 pv;
          pv.x = pk4(pbh[0], pbh[1], pbh[2], pbh[3]);
          pv.y = pk4(pbl[0], pbl[1], pbl[2], pbl[3]);
          st128_cp(hn + ((long)b << 10) + rowt_o * 8, pv);  // s==255: par_w==0 plane = FC input
        }
      }
      if (s < 255) arriveflag(flagsB, (unsigned)(s + 1));
      else arrivecnt(C_FIN);
    }
  }
  waitcnt_(C_FIN, NBLK);

  // ================= FC =================
  if (bid < 128 && wid == 0) {
    const int b = bid;
    const int c0 = l * 2;  // two 16B chunks = units l*8 .. l*8+7
    const u16* pl0 = hl1 + ((long)b << 10);
    u64 h0 = at_ld64(pl0 + c0 * 8);
    u64 l0_ = at_ld64(pl0 + c0 * 8 + 4);
    u64 h1 = at_ld64(pl0 + (c0 + 1) * 8);
    u64 l1_ = at_ld64(pl0 + (c0 + 1) * 8 + 4);
    float ssum = 0.f;
#pragma unroll
    for (int e = 0; e < 8; ++e) {
      int j = l * 8 + e;
      u16 hh = (u16)(((e < 4 ? h0 : h1) >> ((e & 3) * 16)) & 0xFFFF);
      u16 hl_ = (u16)(((e < 4 ? l0_ : l1_) >> ((e & 3) * 16)) & 0xFFFF);
      float hf = bf2f(hh) + bf2f(hl_);
      unsigned hbu = at_ld32(h1bf32 + (long)b * 512 + j);
      ssum += hf * fcw[j] + __builtin_bit_cast(float, hbu) * fcw[512 + j];
    }
#pragma unroll
    for (int off = 32; off; off >>= 1) ssum += __shfl_down(ssum, off);
    if (l == 0) out[b] = ssum + fcb[0];
  }
}

extern "C" void kernel_launch(void* const* d_in, const int* in_sizes, int n_in,
                              void* d_out, int out_size, void* d_ws, size_t ws_size,
                              hipStream_t stream) {
  const float* x     = (const float*)d_in[0];
  const float* wih0f = (const float*)d_in[1];
  const float* whh0f = (const float*)d_in[2];
  const float* b0f   = (const float*)d_in[3];
  const float* wih0b = (const float*)d_in[4];
  const float* whh0b = (const float*)d_in[5];
  const float* b0b   = (const float*)d_in[6];
  const float* wih1f = (const float*)d_in[7];
  const float* whh1f = (const float*)d_in[8];
  const float* b1f   = (const float*)d_in[9];
  const float* wih1b = (const float*)d_in[10];
  const float* whh1b = (const float*)d_in[11];
  const float* b1b   = (const float*)d_in[12];
  const float* fcw   = (const float*)d_in[13];
  const float* fcb   = (const float*)d_in[14];
  float* out = (float*)d_out;

  char* p = (char*)d_ws;
  auto alloc = [&](size_t bytes) {
    char* r = p;
    p += (bytes + 255) & ~(size_t)255;
    return r;
  };
  u16* xpack   = (u16*)alloc(128L * 256 * 64 * 2);
  u16* wih0f_p = (u16*)alloc(128L * 2 * 2 * 512 * 2);
  u16* wih0b_p = (u16*)alloc(128L * 2 * 2 * 512 * 2);
  u16* whh0f_p = (u16*)alloc(128L * 16 * 2 * 512 * 2);
  u16* whh0b_p = (u16*)alloc(128L * 16 * 2 * 512 * 2);
  u16* wih1f_p = (u16*)alloc(128L * 32 * 2 * 512 * 2);
  u16* whh1f_p = (u16*)alloc(128L * 16 * 2 * 512 * 2);
  u16* wih1b_p = (u16*)alloc(128L * 32 * 2 * 512 * 2);
  u16* whh1b_p = (u16*)alloc(128L * 16 * 2 * 512 * 2);
  float* biasP = (float*)alloc(8192 * 4);
  u16* hl0     = (u16*)alloc(4L * PLANE * 2);  // [par][dir] interleaved planes
  u16* hl1     = (u16*)alloc(2L * PLANE * 2);  // [par]
  float* h1bf32= (float*)alloc(128L * 512 * 4);
  unsigned* flagsA = (unsigned*)alloc(256L * 64 * 4);
  unsigned* flagsB = (unsigned*)alloc(256L * 64 * 4);
  unsigned* cnt    = (unsigned*)alloc(128 * 4);
  u16* h0arch  = (u16*)alloc(256L * 128 * 1024 * 2);

  pack_w<true><<<64, 256, 0, stream>>>(wih0f, wih0f_p, 64);
  pack_w<true><<<64, 256, 0, stream>>>(wih0b, wih0b_p, 64);
  pack_w<false><<<512, 256, 0, stream>>>(whh0f, whh0f_p, 512);
  pack_w<false><<<512, 256, 0, stream>>>(whh0b, whh0b_p, 512);
  pack_w<true><<<1024, 256, 0, stream>>>(wih1f, wih1f_p, 1024);
  pack_w<true><<<1024, 256, 0, stream>>>(wih1b, wih1b_p, 1024);
  pack_w<false><<<512, 256, 0, stream>>>(whh1f, whh1f_p, 512);
  pack_w<false><<<512, 256, 0, stream>>>(whh1b, whh1b_p, 512);
  pack_x<<<8192, 256, 0, stream>>>(x, xpack);
  pack_bias<<<32, 256, 0, stream>>>(b0f, b0b, b1f, b1b, biasP);

  (void)hipMemsetAsync(flagsA, 0, 256L * 64 * 4, stream);
  (void)hipMemsetAsync(flagsB, 0, 256L * 64 * 4, stream);
  (void)hipMemsetAsync(cnt, 0, 128 * 4, stream);

  lstm_persist<<<NBLK, 512, 0, stream>>>(
      xpack, h0arch,
      wih0f_p, wih0b_p, whh0f_p, whh0b_p,
      wih1f_p, whh1f_p, wih1b_p, whh1b_p,
      biasP, hl0, hl1, h1bf32,
      fcw, fcb, out, flagsA, flagsB, cnt);
}

// Round 15
// 3107.398 us; speedup vs baseline: 1.5965x; 1.0055x over previous
//
#include <hip/hip_runtime.h>

#define NBLK 256
#define PLANE 131072  // u16 elems per interleaved h plane: 128 b x (512 hi + 512 lo)

typedef unsigned short u16;
typedef unsigned long long u64;
typedef __attribute__((ext_vector_type(8))) short bf16x8;
typedef __attribute__((ext_vector_type(8))) _Float16 f16x8;
typedef __attribute__((ext_vector_type(4))) float f32x4;
typedef __attribute__((ext_vector_type(2))) unsigned long long u64x2;

#define MFMA_F16(a, b, c) __builtin_amdgcn_mfma_f32_16x16x32_f16(a, b, c, 0, 0, 0)
#define MFMA_BF16(a, b, c) __builtin_amdgcn_mfma_f32_16x16x32_bf16(a, b, c, 0, 0, 0)

__device__ __forceinline__ float fsig(float x) { return 1.f / (1.f + __expf(-x)); }
__device__ __forceinline__ float ftanh(float x) {
  float e = __expf(2.f * x);
  return 1.f - 2.f / (e + 1.f);
}
__device__ __forceinline__ u16 f2bf(float f) {
  unsigned u = __builtin_bit_cast(unsigned, f);
  return (u16)((u + 0x7FFFu + ((u >> 16) & 1)) >> 16);
}
__device__ __forceinline__ float bf2f(u16 h) {
  unsigned u = ((unsigned)h) << 16;
  return __builtin_bit_cast(float, u);
}
__device__ __forceinline__ u16 f2h(float f) {
  _Float16 h = (_Float16)f;
  return __builtin_bit_cast(u16, h);
}

__device__ __forceinline__ u64 at_ld64(const void* p) {
  return __hip_atomic_load((const u64*)p, __ATOMIC_RELAXED, __HIP_MEMORY_SCOPE_AGENT);
}
__device__ __forceinline__ void at_st64(void* p, u64 v) {
  __hip_atomic_store((u64*)p, v, __ATOMIC_RELAXED, __HIP_MEMORY_SCOPE_AGENT);
}
__device__ __forceinline__ unsigned at_ld32(const void* p) {
  return __hip_atomic_load((const unsigned*)p, __ATOMIC_RELAXED, __HIP_MEMORY_SCOPE_AGENT);
}
__device__ __forceinline__ void at_st32(void* p, unsigned v) {
  __hip_atomic_store((unsigned*)p, v, __ATOMIC_RELAXED, __HIP_MEMORY_SCOPE_AGENT);
}
__device__ __forceinline__ u64 pk4(u16 a, u16 b, u16 c, u16 d) {
  return (u64)a | ((u64)b << 16) | ((u64)c << 32) | ((u64)d << 48);
}
__device__ __forceinline__ u64 pkf2(float a, float b) {
  return (u64)__builtin_bit_cast(unsigned, a) | ((u64)__builtin_bit_cast(unsigned, b) << 32);
}
// 16B coherence-point store (L3)
__device__ __forceinline__ void st128_cp(u16* p, u64x2 v) {
  asm volatile("global_store_dwordx4 %0, %1, off sc0 sc1" :: "v"(p), "v"(v) : "memory");
}

// ---- pack weights [2048][K] fp32 -> fragment-major hi/lo ----
template <bool F16>
__global__ void pack_w(const float* __restrict__ W, u16* __restrict__ dst, int K) {
  int NKT = K >> 5;
  long gid = (long)blockIdx.x * 256 + threadIdx.x;
  long total = (long)128 * NKT * 64;
  if (gid >= total) return;
  int lane = gid & 63;
  int kt = (gid >> 6) % NKT;
  int rt = (gid >> 6) / NKT;
  int r = lane & 15;
  int grow = (r >> 2) * 512 + rt * 4 + (r & 3);
  int k0 = kt * 32 + (lane >> 4) * 8;
  long base = ((long)(rt * NKT + kt) * 2) * 512 + lane * 8;
#pragma unroll
  for (int e = 0; e < 8; ++e) {
    float w = W[(long)grow * K + k0 + e];
    u16 hi, lo;
    if (F16) {
      _Float16 h = (_Float16)w;
      hi = __builtin_bit_cast(u16, h);
      _Float16 l2 = (_Float16)(w - (float)h);
      lo = __builtin_bit_cast(u16, l2);
    } else {
      hi = f2bf(w);
      lo = f2bf(w - bf2f(hi));
    }
    dst[base + e] = hi;
    dst[base + 512 + e] = lo;
  }
}

__global__ void pack_x(const float* __restrict__ x, u16* __restrict__ xp) {
  long gid = (long)blockIdx.x * 256 + threadIdx.x;
  if (gid >= 128L * 256 * 64) return;
  int k = gid & 63;
  long bt = gid >> 6;
  int t = bt & 255;
  int b = bt >> 8;
  xp[((long)t * 128 + b) * 64 + k] = f2h(x[((long)b * 256 + t) * 64 + k]);
}

__global__ void pack_bias(const float* __restrict__ b0f, const float* __restrict__ b0b,
                          const float* __restrict__ b1f, const float* __restrict__ b1b,
                          float* __restrict__ bp) {
  int gid = blockIdx.x * 256 + threadIdx.x;
  if (gid >= 8192) return;
  int src = gid >> 11;
  int idx = gid & 2047;
  int rt = idx >> 4, rr = idx & 15;
  int grow = (rr >> 2) * 512 + rt * 4 + (rr & 3);
  const float* B = (src == 0) ? b0f : (src == 1) ? b0b : (src == 2) ? b1f : b1b;
  bp[gid] = B[grow];
}

#define C_TRANS 0
#define C_FIN 64

// ---- persistent kernel: VGPR weights, 16B sc1 exchange, pipelined x-projection ----
__global__ __launch_bounds__(512, 2) void lstm_persist(
    const u16* __restrict__ xpack, u16* __restrict__ h0arch,
    const u16* __restrict__ wih0f_p, const u16* __restrict__ wih0b_p,
    const u16* __restrict__ whh0f_p, const u16* __restrict__ whh0b_p,
    const u16* __restrict__ wih1f_p, const u16* __restrict__ whh1f_p,
    const u16* __restrict__ wih1b_p, const u16* __restrict__ whh1b_p,
    const float* __restrict__ biasP,
    u16* __restrict__ hl0, u16* __restrict__ hl1,
    float* __restrict__ h1bf32,
    const float* __restrict__ fcw, const float* __restrict__ fcb,
    float* __restrict__ out,
    unsigned* __restrict__ flagsA, unsigned* __restrict__ flagsB,
    unsigned* __restrict__ cnt) {
  const int bid = blockIdx.x;
  const int xcd = bid & 7, slot = bid >> 3;
  const int tid = threadIdx.x;
  const int wid = tid >> 6, l = tid & 63;
  const int c = l & 15, q = l >> 4;

  __shared__ __align__(16) char smem[65536];       // h staging [hi 32K | lo 32K]
  __shared__ __align__(16) f32x4 shacc[8][2][64];  // 16 KB K-slice reduce

  const f32x4 fz = {0.f, 0.f, 0.f, 0.f};

  auto arriveflag = [&](unsigned* fl, unsigned gen) {
    asm volatile("s_waitcnt vmcnt(0)" ::: "memory");
    __syncthreads();
    if (tid == 0) at_st32(fl + (long)bid * 64, gen);
  };
  auto waitflags = [&](const unsigned* fl, int base, int nmem, unsigned gen) {
    if (wid == 0) {
      unsigned f;
      do {
        f = (l < nmem) ? at_ld32(fl + (long)(base + l) * 64) : gen;
      } while (__ballot(f < gen));
    }
    __syncthreads();
  };
  auto arrivecnt = [&](int idx) {
    asm volatile("s_waitcnt vmcnt(0)" ::: "memory");
    __syncthreads();
    if (tid == 0)
      __hip_atomic_fetch_add(cnt + idx, 1u, __ATOMIC_RELAXED, __HIP_MEMORY_SCOPE_AGENT);
  };
  auto waitcnt_ = [&](int idx, unsigned tgt) {
    if (tid == 0) {
      while (at_ld32(cnt + idx) < tgt) __builtin_amdgcn_s_sleep(1);
    }
    __syncthreads();
  };
  // stage 32 batches: 8x 16B sc1 loads, de-interleave to smem hi/lo
  auto stage16 = [&](const u16* plane, int b0blk) {
    u64x2 vv[8];
#pragma unroll
    for (int i = 0; i < 8; ++i) {
      int m = tid + (i << 9);
      int b = m >> 7, cb = m & 127;
      const u16* src = plane + ((long)(b0blk + b) << 10) + (cb << 3);
      asm volatile("global_load_dwordx4 %0, %1, off sc0 sc1"
                   : "=v"(vv[i]) : "v"(src) : "memory");
    }
    asm volatile("s_waitcnt vmcnt(0)" ::: "memory");
    __builtin_amdgcn_sched_barrier(0);
#pragma unroll
    for (int i = 0; i < 8; ++i) {
      int m = tid + (i << 9);
      int b = m >> 7, cb = m & 127;
      int ahi = ((b << 10) | (cb << 3)) ^ ((b & 7) << 4);
      *(u64*)(smem + ahi) = vv[i].x;
      *(u64*)(smem + 32768 + ahi) = vv[i].y;
    }
  };

  // ================= Phase L0: 256 steps, both dirs, 8 groups of 32 =================
  {
    const int d = slot >> 4;
    const int bg = (slot >> 2) & 3;
    const int gbase = d * 128 + bg * 32;
    const int ug = xcd * 4 + (slot & 3);
    const int rowt = ug * 4 + (wid >> 1);
    const int kh = wid & 1;
    const u16* wxp = d ? wih0b_p : wih0f_p;
    const u16* whp = d ? whh0b_p : whh0f_p;
    const int b0e = bg * 32 + kh * 16;
    const float* bp = biasP + ((long)d * 128 + rowt) * 16 + q * 4;

    // preload weights into registers
    f16x8 wxh, wxl;
    {
      const u16* a = wxp + ((long)(rowt * 2 + kh) * 2) * 512 + l * 8;
      wxh = *(const f16x8*)a;
      wxl = *(const f16x8*)(a + 512);
    }
    bf16x8 whh_r[8], whl_r[8];
#pragma unroll
    for (int j = 0; j < 8; ++j) {
      const u16* a = whp + ((long)(rowt * 16 + kh * 8 + j) * 2) * 512 + l * 8;
      whh_r[j] = *(const bf16x8*)a;
      whl_r[j] = *(const bf16x8*)(a + 512);
    }

    const int sw = (c & 7) << 4;
    const int cq0 = (c << 10) | (q << 4);
    const int cq1 = ((16 + c) << 10) | (q << 4);

    // x-projection for step ss -> o0/o1 (VGPR weights, L2-cached xpack; no smem)
    auto xproj = [&](int ss, f32x4& o0, f32x4& o1) {
      const int tt = d ? 255 - ss : ss;
      const u16* xb = xpack + ((long)tt * 128 + bg * 32 + c) * 64 + kh * 32 + q * 8;
      f16x8 bx0 = *(const f16x8*)xb;
      f16x8 bx1 = *(const f16x8*)(xb + 16 * 64);
      o0 = MFMA_F16(wxh, bx0, fz);
      o0 = MFMA_F16(wxl, bx0, o0);
      o1 = MFMA_F16(wxh, bx1, fz);
      o1 = MFMA_F16(wxl, bx1, o1);
    };

    float c_reg[4] = {0.f, 0.f, 0.f, 0.f};
    f32x4 xa0, xa1;
    xproj(0, xa0, xa1);  // prologue
    for (int s = 0; s < 256; ++s) {
      const int par = s & 1;
      f32x4 acc0 = xa0, acc1 = xa1;  // carried x-projection
      if (s) {
        waitflags(flagsA, gbase, 32, s);
        stage16(hl0 + (long)(par * 2 + d) * PLANE, bg * 32);
        __syncthreads();
#pragma unroll
        for (int j = 0; j < 8; ++j) {
          const int kt = kh * 8 + j;
          const int b0a = (cq0 | (kt << 6)) ^ sw;
          const int b1a = (cq1 | (kt << 6)) ^ sw;
          bf16x8 bhi0 = *(const bf16x8*)(smem + b0a);
          bf16x8 blo0 = *(const bf16x8*)(smem + 32768 + b0a);
          bf16x8 bhi1 = *(const bf16x8*)(smem + b1a);
          bf16x8 blo1 = *(const bf16x8*)(smem + 32768 + b1a);
          acc0 = MFMA_BF16(whh_r[j], bhi0, acc0);
          acc0 = MFMA_BF16(whl_r[j], bhi0, acc0);
          acc0 = MFMA_BF16(whh_r[j], blo0, acc0);
          acc1 = MFMA_BF16(whh_r[j], bhi1, acc1);
          acc1 = MFMA_BF16(whl_r[j], bhi1, acc1);
          acc1 = MFMA_BF16(whh_r[j], blo1, acc1);
        }
      }
      shacc[wid][0][l] = acc0;
      shacc[wid][1][l] = acc1;
      __syncthreads();
      {
        const int pr = (wid >> 1) * 2;
        const int bo = wid & 1;
        f32x4 tot = shacc[pr][bo][l] + shacc[pr + 1][bo][l];
        float pre[4];
#pragma unroll
        for (int i = 0; i < 4; ++i) pre[i] = tot[i] + bp[i];
        const int par_w = par ^ 1;
        u16* hn = hl0 + (long)(par_w * 2 + d) * PLANE;
        const int b = b0e + c;
        const int t = d ? 255 - s : s;
        u16 pbh[4], pbl[4], pf[4];
#pragma unroll
        for (int i = 0; i < 4; ++i) {
          float gI = __shfl(pre[i], c);
          float gF = __shfl(pre[i], c + 16);
          float gG = __shfl(pre[i], c + 32);
          float gO = __shfl(pre[i], c + 48);
          float cn = fsig(gF) * c_reg[i] + fsig(gI) * ftanh(gG);
          c_reg[i] = cn;
          float hv = fsig(gO) * ftanh(cn);
          u16 hh = f2bf(hv);
          pbh[i] = hh;
          pbl[i] = f2bf(hv - bf2f(hh));
          pf[i] = f2h(hv);
        }
        if (q == 0) {
          if (s < 255) {
            u64x2 pv;
            pv.x = pk4(pbh[0], pbh[1], pbh[2], pbh[3]);
            pv.y = pk4(pbl[0], pbl[1], pbl[2], pbl[3]);
            st128_cp(hn + ((long)b << 10) + rowt * 8, pv);
          }
          at_st64(h0arch + ((long)t * 128 + b) * 1024 + d * 512 + rowt * 4,
                  pk4(pf[0], pf[1], pf[2], pf[3]));
        }
      }
      // pipelined x-projection for s+1: overlaps the h-store drain + flag RT below
      if (s < 255) xproj(s + 1, xa0, xa1);
      if (s < 255) arriveflag(flagsA, (unsigned)(s + 1));
      else arrivecnt(C_TRANS);
    }
  }
  waitcnt_(C_TRANS, NBLK);
  __threadfence();  // one-time inv: plain h0arch reads below see fresh data
  __syncthreads();

  // ================= Phase L1B: single step t=255 (zero state) =================
  {
    const int ug1 = xcd * 8 + (slot & 7);
    const int bg1 = slot >> 3;
    const int rl1 = (wid >> 1) & 1;
    const int btl1 = wid & 1;
    const int kh = wid >> 2;
    const int rowt1 = ug1 * 2 + rl1;
    const int b01 = bg1 * 32 + btl1 * 16;
    f32x4 a0 = fz, a1 = fz;
    const u16* bbase = h0arch + (255L * 128 + b01 + c) * 1024 + q * 8;
#pragma unroll
    for (int kk = 0; kk < 16; ++kk) {
      int kt = kh * 16 + kk;
      const u16* a = wih1b_p + ((long)(rowt1 * 32 + kt) * 2) * 512 + l * 8;
      f16x8 ahi = *(const f16x8*)a;
      f16x8 alo = *(const f16x8*)(a + 512);
      f16x8 bx = *(const f16x8*)(bbase + kt * 32);
      f32x4& t0 = (kk & 1) ? a1 : a0;
      t0 = MFMA_F16(ahi, bx, t0);
      t0 = MFMA_F16(alo, bx, t0);
    }
    f32x4 acc = a0 + a1;
    shacc[wid][0][l] = acc;
    __syncthreads();
    if (wid < 4) {
      f32x4 tot = shacc[wid][0][l] + shacc[wid + 4][0][l];
      const float* bp1 = biasP + (3L * 128 + rowt1) * 16 + q * 4;
      float pre[4];
#pragma unroll
      for (int i = 0; i < 4; ++i) pre[i] = tot[i] + bp1[i];
      const int b = b01 + c;
      float hv[4];
#pragma unroll
      for (int i = 0; i < 4; ++i) {
        float gI = __shfl(pre[i], c);
        float gG = __shfl(pre[i], c + 32);
        float gO = __shfl(pre[i], c + 48);
        float cn = fsig(gI) * ftanh(gG);
        hv[i] = fsig(gO) * ftanh(cn);
      }
      if (q == 0) {
        at_st64((u16*)(h1bf32 + (long)b * 512 + rowt1 * 4), pkf2(hv[0], hv[1]));
        at_st64((u16*)(h1bf32 + (long)b * 512 + rowt1 * 4 + 2), pkf2(hv[2], hv[3]));
      }
    }
    __syncthreads();
  }

  // ================= Phase L1F: 256 steps, 4 groups of 64, weights in regs ==========
  {
    const int ug1 = xcd * 8 + (slot & 7);
    const int bg1 = slot >> 3;
    const int g1base = bg1 * 64;
    const int rl1 = wid & 1;
    const int kh1 = wid >> 1;
    const int rowt1 = ug1 * 2 + rl1;

    f16x8 w1h[8], w1l[8];
#pragma unroll
    for (int j = 0; j < 8; ++j) {
      const u16* a = wih1f_p + ((long)(rowt1 * 32 + kh1 * 8 + j) * 2) * 512 + l * 8;
      w1h[j] = *(const f16x8*)a;
      w1l[j] = *(const f16x8*)(a + 512);
    }
    bf16x8 v1h[4], v1l[4];
#pragma unroll
    for (int j = 0; j < 4; ++j) {
      const u16* a = whh1f_p + ((long)(rowt1 * 16 + kh1 * 4 + j) * 2) * 512 + l * 8;
      v1h[j] = *(const bf16x8*)a;
      v1l[j] = *(const bf16x8*)(a + 512);
    }

    const int sw = (c & 7) << 4;
    const int cq0 = (c << 10) | (q << 4);
    const int cq1 = ((16 + c) << 10) | (q << 4);
    const int rl_o = wid & 1;
    const int bt_o = wid >> 1;
    const int rowt_o = ug1 * 2 + rl_o;
    const float* bp1 = biasP + (2L * 128 + rowt_o) * 16 + q * 4;

    // h0 projection for step ss (VGPR weights, plain-cached h0arch; no smem)
    auto xproj = [&](int ss, f32x4& o0, f32x4& o1) {
      const u16* hb = h0arch + ((long)ss * 128 + bg1 * 32 + c) * 1024 + q * 8;
      o0 = fz;
      o1 = fz;
#pragma unroll
      for (int j = 0; j < 8; ++j) {
        const int kt = kh1 * 8 + j;
        f16x8 bx0 = *(const f16x8*)(hb + kt * 32);
        f16x8 bx1 = *(const f16x8*)(hb + 16 * 1024 + kt * 32);
        o0 = MFMA_F16(w1h[j], bx0, o0);
        o0 = MFMA_F16(w1l[j], bx0, o0);
        o1 = MFMA_F16(w1h[j], bx1, o1);
        o1 = MFMA_F16(w1l[j], bx1, o1);
      }
    };

    float c_reg[4] = {0.f, 0.f, 0.f, 0.f};
    f32x4 xa0, xa1;
    xproj(0, xa0, xa1);  // prologue
    for (int s = 0; s < 256; ++s) {
      const int par = s & 1;
      f32x4 acc0 = xa0, acc1 = xa1;
      if (s) {
        waitflags(flagsB, g1base, 64, s);
        stage16(hl1 + (long)par * PLANE, bg1 * 32);
        __syncthreads();
#pragma unroll
        for (int j = 0; j < 4; ++j) {
          const int kt = kh1 * 4 + j;
          const int b0a = (cq0 | (kt << 6)) ^ sw;
          const int b1a = (cq1 | (kt << 6)) ^ sw;
          bf16x8 bhi0 = *(const bf16x8*)(smem + b0a);
          bf16x8 blo0 = *(const bf16x8*)(smem + 32768 + b0a);
          bf16x8 bhi1 = *(const bf16x8*)(smem + b1a);
          bf16x8 blo1 = *(const bf16x8*)(smem + 32768 + b1a);
          acc0 = MFMA_BF16(v1h[j], bhi0, acc0);
          acc0 = MFMA_BF16(v1l[j], bhi0, acc0);
          acc0 = MFMA_BF16(v1h[j], blo0, acc0);
          acc1 = MFMA_BF16(v1h[j], bhi1, acc1);
          acc1 = MFMA_BF16(v1l[j], bhi1, acc1);
          acc1 = MFMA_BF16(v1h[j], blo1, acc1);
        }
      }
      shacc[wid][0][l] = acc0;
      shacc[wid][1][l] = acc1;
      __syncthreads();
      if (wid < 4) {
        f32x4 tot = shacc[rl_o][bt_o][l] + shacc[2 + rl_o][bt_o][l] +
                    shacc[4 + rl_o][bt_o][l] + shacc[6 + rl_o][bt_o][l];
        float pre[4];
#pragma unroll
        for (int i = 0; i < 4; ++i) pre[i] = tot[i] + bp1[i];
        const int par_w = par ^ 1;
        u16* hn = hl1 + (long)par_w * PLANE;
        const int b = bg1 * 32 + bt_o * 16 + c;
        u16 pbh[4], pbl[4];
#pragma unroll
        for (int i = 0; i < 4; ++i) {
          float gI = __shfl(pre[i], c);
          float gF = __shfl(pre[i], c + 16);
          float gG = __shfl(pre[i], c + 32);
          float gO = __shfl(pre[i], c + 48);
          float cn = fsig(gF) * c_reg[i] + fsig(gI) * ftanh(gG);
          c_reg[i] = cn;
          float hv = fsig(gO) * ftanh(cn);
          u16 hh = f2bf(hv);
          pbh[i] = hh;
          pbl[i] = f2bf(hv - bf2f(hh));
        }
        if (q == 0) {
          u64x2 pv;
          pv.x = pk4(pbh[0], pbh[1], pbh[2], pbh[3]);
          pv.y = pk4(pbl[0], pbl[1], pbl[2], pbl[3]);
          st128_cp(hn + ((long)b << 10) + rowt_o * 8, pv);  // s==255: par_w==0 = FC input
        }
      }
      if (s < 255) xproj(s + 1, xa0, xa1);  // overlaps drain + flag RT
      if (s < 255) arriveflag(flagsB, (unsigned)(s + 1));
      else arrivecnt(C_FIN);
    }
  }
  waitcnt_(C_FIN, NBLK);

  // ================= FC =================
  if (bid < 128 && wid == 0) {
    const int b = bid;
    const int c0 = l * 2;
    const u16* pl0 = hl1 + ((long)b << 10);
    u64 h0 = at_ld64(pl0 + c0 * 8);
    u64 l0_ = at_ld64(pl0 + c0 * 8 + 4);
    u64 h1 = at_ld64(pl0 + (c0 + 1) * 8);
    u64 l1_ = at_ld64(pl0 + (c0 + 1) * 8 + 4);
    float ssum = 0.f;
#pragma unroll
    for (int e = 0; e < 8; ++e) {
      int j = l * 8 + e;
      u16 hh = (u16)(((e < 4 ? h0 : h1) >> ((e & 3) * 16)) & 0xFFFF);
      u16 hl_ = (u16)(((e < 4 ? l0_ : l1_) >> ((e & 3) * 16)) & 0xFFFF);
      float hf = bf2f(hh) + bf2f(hl_);
      unsigned hbu = at_ld32(h1bf32 + (long)b * 512 + j);
      ssum += hf * fcw[j] + __builtin_bit_cast(float, hbu) * fcw[512 + j];
    }
#pragma unroll
    for (int off = 32; off; off >>= 1) ssum += __shfl_down(ssum, off);
    if (l == 0) out[b] = ssum + fcb[0];
  }
}

extern "C" void kernel_launch(void* const* d_in, const int* in_sizes, int n_in,
                              void* d_out, int out_size, void* d_ws, size_t ws_size,
                              hipStream_t stream) {
  const float* x     = (const float*)d_in[0];
  const float* wih0f = (const float*)d_in[1];
  const float* whh0f = (const float*)d_in[2];
  const float* b0f   = (const float*)d_in[3];
  const float* wih0b = (const float*)d_in[4];
  const float* whh0b = (const float*)d_in[5];
  const float* b0b   = (const float*)d_in[6];
  const float* wih1f = (const float*)d_in[7];
  const float* whh1f = (const float*)d_in[8];
  const float* b1f   = (const float*)d_in[9];
  const float* wih1b = (const float*)d_in[10];
  const float* whh1b = (const float*)d_in[11];
  const float* b1b   = (const float*)d_in[12];
  const float* fcw   = (const float*)d_in[13];
  const float* fcb   = (const float*)d_in[14];
  float* out = (float*)d_out;

  char* p = (char*)d_ws;
  auto alloc = [&](size_t bytes) {
    char* r = p;
    p += (bytes + 255) & ~(size_t)255;
    return r;
  };
  u16* xpack   = (u16*)alloc(128L * 256 * 64 * 2);
  u16* wih0f_p = (u16*)alloc(128L * 2 * 2 * 512 * 2);
  u16* wih0b_p = (u16*)alloc(128L * 2 * 2 * 512 * 2);
  u16* whh0f_p = (u16*)alloc(128L * 16 * 2 * 512 * 2);
  u16* whh0b_p = (u16*)alloc(128L * 16 * 2 * 512 * 2);
  u16* wih1f_p = (u16*)alloc(128L * 32 * 2 * 512 * 2);
  u16* whh1f_p = (u16*)alloc(128L * 16 * 2 * 512 * 2);
  u16* wih1b_p = (u16*)alloc(128L * 32 * 2 * 512 * 2);
  u16* whh1b_p = (u16*)alloc(128L * 16 * 2 * 512 * 2);
  float* biasP = (float*)alloc(8192 * 4);
  u16* hl0     = (u16*)alloc(4L * PLANE * 2);  // [par][dir] interleaved planes
  u16* hl1     = (u16*)alloc(2L * PLANE * 2);  // [par]
  float* h1bf32= (float*)alloc(128L * 512 * 4);
  unsigned* flagsA = (unsigned*)alloc(256L * 64 * 4);
  unsigned* flagsB = (unsigned*)alloc(256L * 64 * 4);
  unsigned* cnt    = (unsigned*)alloc(128 * 4);
  u16* h0arch  = (u16*)alloc(256L * 128 * 1024 * 2);

  pack_w<true><<<64, 256, 0, stream>>>(wih0f, wih0f_p, 64);
  pack_w<true><<<64, 256, 0, stream>>>(wih0b, wih0b_p, 64);
  pack_w<false><<<512, 256, 0, stream>>>(whh0f, whh0f_p, 512);
  pack_w<false><<<512, 256, 0, stream>>>(whh0b, whh0b_p, 512);
  pack_w<true><<<1024, 256, 0, stream>>>(wih1f, wih1f_p, 1024);
  pack_w<true><<<1024, 256, 0, stream>>>(wih1b, wih1b_p, 1024);
  pack_w<false><<<512, 256, 0, stream>>>(whh1f, whh1f_p, 512);
  pack_w<false><<<512, 256, 0, stream>>>(whh1b, whh1b_p, 512);
  pack_x<<<8192, 256, 0, stream>>>(x, xpack);
  pack_bias<<<32, 256, 0, stream>>>(b0f, b0b, b1f, b1b, biasP);

  (void)hipMemsetAsync(flagsA, 0, 256L * 64 * 4, stream);
  (void)hipMemsetAsync(flagsB, 0, 256L * 64 * 4, stream);
  (void)hipMemsetAsync(cnt, 0, 128 * 4, stream);

  lstm_persist<<<NBLK, 512, 0, stream>>>(
      xpack, h0arch,
      wih0f_p, wih0b_p, whh0f_p, whh0b_p,
      wih1f_p, whh1f_p, wih1b_p, whh1b_p,
      biasP, hl0, hl1, h1bf32,
      fcw, fcb, out, flagsA, flagsB, cnt);
}